// Round 1
// baseline (521.168 us; speedup 1.0000x reference)
//
#include <hip/hip_runtime.h>
#include <hip/hip_bf16.h>
#include <math.h>

typedef unsigned int uint;
typedef unsigned short ushort_t;
typedef unsigned char uchar;

typedef __attribute__((ext_vector_type(4))) float f4_t;
typedef __attribute__((ext_vector_type(4))) ushort_t u16x4_t;
typedef __attribute__((ext_vector_type(4))) uint u32x4_t;
typedef __attribute__((ext_vector_type(8))) short bfrag_t;
typedef __attribute__((ext_vector_type(4))) float facc_t;

#define K_DIM 2048
#define D_DIM 256
#define E_DIM 64
#define N_DIM 320
#define S_DIM 4096
#define NTOK 16384
#define KSEL 4096

__device__ __forceinline__ ushort_t f2bf(float f) {
  uint u = __float_as_uint(f);
  uint r = u + 0x7FFFu + ((u >> 16) & 1u);  // RNE
  return (ushort_t)(r >> 16);
}

// ---------------- prep: convert weights to bf16, zero accumulators ----------
__global__ __launch_bounds__(256) void prep_kernel(
    const float* __restrict__ W_ts, const float* __restrict__ W_tr,
    ushort_t* __restrict__ Wc, float* __restrict__ zero_region)
{
  int idx = blockIdx.x * 256 + threadIdx.x;       // over N_DIM*K_DIM/4 float4s
  if (idx < (N_DIM * K_DIM / 4)) {
    int n = idx >> 9;                              // / (2048/4)
    int k4 = (idx & 511) * 4;
    const float* src = (n < D_DIM) ? (W_ts + (size_t)n * K_DIM + k4)
                                   : (W_tr + (size_t)(n - D_DIM) * K_DIM + k4);
    f4_t v = *reinterpret_cast<const f4_t*>(src);
    u16x4_t h;
    h[0] = f2bf(v[0]); h[1] = f2bf(v[1]); h[2] = f2bf(v[2]); h[3] = f2bf(v[3]);
    *reinterpret_cast<u16x4_t*>(&Wc[(size_t)n * K_DIM + k4]) = h;
  }
  if (blockIdx.x == 0) {
    for (int i = threadIdx.x; i < 2560; i += 256) zero_region[i] = 0.f;
  }
}

// ---------------- fused GEMM: base_logits + pooled tanh(token_state) --------
#define BM 64
#define BK 64
#define LDK 72   // padded row stride in halfs (144 B: 16B-aligned, bank-spread)

__global__ __launch_bounds__(640) void gemm_kernel(
    const float* __restrict__ hidden, const ushort_t* __restrict__ Wc,
    const float* __restrict__ b_ts, const float* __restrict__ b_tr,
    float* __restrict__ base_logits, float* __restrict__ pooled_ts)
{
  __shared__ ushort_t Alds[BM * LDK];      //  9216 B
  __shared__ ushort_t Blds[N_DIM * LDK];   // 46080 B
  const int tid = threadIdx.x;
  const int lane = tid & 63;
  const int w = tid >> 6;        // 0..9
  const int wc = w % 5;          // N-slice of 64
  const int wrr = w / 5;         // M-slice of 32
  const int row0 = blockIdx.x * BM;
  const int lr = lane & 15;
  const int lgp = lane >> 4;

  facc_t acc[2][4];
#pragma unroll
  for (int mi = 0; mi < 2; mi++)
#pragma unroll
    for (int ni = 0; ni < 4; ni++) acc[mi][ni] = (facc_t){0.f, 0.f, 0.f, 0.f};

  for (int k0 = 0; k0 < K_DIM; k0 += BK) {
    // stage A (f32 -> bf16): 64 rows x 64 k = 1024 float4
#pragma unroll 2
    for (int idx = tid; idx < (BM * BK / 4); idx += 640) {
      int r = idx >> 4, c4 = idx & 15;
      f4_t v = *reinterpret_cast<const f4_t*>(hidden + (size_t)(row0 + r) * K_DIM + k0 + c4 * 4);
      u16x4_t h;
      h[0] = f2bf(v[0]); h[1] = f2bf(v[1]); h[2] = f2bf(v[2]); h[3] = f2bf(v[3]);
      *reinterpret_cast<u16x4_t*>(&Alds[r * LDK + c4 * 4]) = h;
    }
    // stage B (already bf16): 320 rows x 64 k = 2560 x 16B
#pragma unroll 4
    for (int idx = tid; idx < (N_DIM * BK / 8); idx += 640) {
      int r = idx >> 3, c8 = idx & 7;
      u32x4_t v = *reinterpret_cast<const u32x4_t*>(Wc + (size_t)r * K_DIM + k0 + c8 * 8);
      *reinterpret_cast<u32x4_t*>(&Blds[r * LDK + c8 * 8]) = v;
    }
    __syncthreads();
#pragma unroll
    for (int kk = 0; kk < 2; ++kk) {
      bfrag_t af[2], bfv[4];
#pragma unroll
      for (int mi = 0; mi < 2; mi++)
        af[mi] = *reinterpret_cast<const bfrag_t*>(&Alds[(wrr * 32 + mi * 16 + lr) * LDK + kk * 32 + lgp * 8]);
#pragma unroll
      for (int ni = 0; ni < 4; ni++)
        bfv[ni] = *reinterpret_cast<const bfrag_t*>(&Blds[(wc * 64 + ni * 16 + lr) * LDK + kk * 32 + lgp * 8]);
#pragma unroll
      for (int mi = 0; mi < 2; mi++)
#pragma unroll
        for (int ni = 0; ni < 4; ni++)
          acc[mi][ni] = __builtin_amdgcn_mfma_f32_16x16x32_bf16(af[mi], bfv[ni], acc[mi][ni], 0, 0, 0);
    }
    __syncthreads();
  }

  const int b = row0 >> 12;  // batch (4096 rows per batch, 64 | 4096)
  if (wc < 4) {
    // token_state columns: tanh then pool (sum over this wave's 32 rows)
#pragma unroll
    for (int ni = 0; ni < 4; ni++) {
      const int col = wc * 64 + ni * 16 + lr;
      const float bias = b_ts[col];
      float psum = 0.f;
#pragma unroll
      for (int mi = 0; mi < 2; mi++)
#pragma unroll
        for (int j = 0; j < 4; j++)
          psum += tanhf(acc[mi][ni][j] + bias);
      psum += __shfl_xor(psum, 16, 64);
      psum += __shfl_xor(psum, 32, 64);
      if (lgp == 0) atomicAdd(&pooled_ts[b * D_DIM + col], psum);
    }
  } else {
    // base logit columns (wc == 4 -> cols 256..319)
#pragma unroll
    for (int ni = 0; ni < 4; ni++) {
      const int e = ni * 16 + lr;
      const float bias = b_tr[e];
#pragma unroll
      for (int mi = 0; mi < 2; mi++)
#pragma unroll
        for (int j = 0; j < 4; j++) {
          const int row = row0 + wrr * 32 + mi * 16 + lgp * 4 + j;
          base_logits[(size_t)row * E_DIM + e] = acc[mi][ni][j] + bias;
        }
    }
  }
}

// ---------------- per-round softmax / margins / pooling ---------------------
__global__ __launch_bounds__(256) void route_kernel(
    int round,
    const float* __restrict__ base_logits,
    const float* __restrict__ bias1, const float* __restrict__ bias2,
    const uchar* __restrict__ active, uchar* __restrict__ tag,
    float* __restrict__ margins, float* __restrict__ pw_out,
    float* __restrict__ out)
{
  __shared__ float sm[4][64];
  const int tid = threadIdx.x;
  const int lane = tid & 63;
  const int wid = tid >> 6;
  const int b = blockIdx.x >> 6;   // 64 tokens/block, 4096 tokens/batch
  float pacc = 0.f;
  for (int i = 0; i < 16; ++i) {
    const int t = blockIdx.x * 64 + wid * 16 + i;
    float lgt = base_logits[(size_t)t * E_DIM + lane];
    if (round == 1) {
      uchar a = active[t];
      if (a) lgt += bias1[b * E_DIM + lane];
      if (lane == 0) tag[t] = a;
    } else if (round == 2) {
      uchar a = active[t];
      if (a) lgt += bias2[b * E_DIM + lane];
      else if (tag[t]) lgt += bias1[b * E_DIM + lane];
    }
    float m1 = lgt;
#pragma unroll
    for (int mm = 32; mm; mm >>= 1) m1 = fmaxf(m1, __shfl_xor(m1, mm, 64));
    float e = expf(lgt - m1);
    float s = e;
#pragma unroll
    for (int mm = 32; mm; mm >>= 1) s += __shfl_xor(s, mm, 64);
    if (round == 2) {
      out[(size_t)t * E_DIM + lane] = e / s;
    } else {
      pacc += e / s;
      unsigned long long bal = __ballot(lgt == m1);
      int first = __ffsll((unsigned long long)bal) - 1;
      float l2 = (lane == first) ? -__builtin_inff() : lgt;
#pragma unroll
      for (int mm = 32; mm; mm >>= 1) l2 = fmaxf(l2, __shfl_xor(l2, mm, 64));
      if (lane == 0) margins[t] = (1.f - expf(l2 - m1)) / s;   // top1-top2 of weights
    }
  }
  if (round != 2) {
    sm[wid][lane] = pacc;
    __syncthreads();
    if (wid == 0) {
      float v = sm[0][lane] + sm[1][lane] + sm[2][lane] + sm[3][lane];
      atomicAdd(&pw_out[b * E_DIM + lane], v);
    }
  }
}

// ---------------- mid: GRU (blocks 0..3) + k-smallest select (block 4) ------
__global__ __launch_bounds__(256) void mid_kernel(
    const float* __restrict__ margins,
    const float* __restrict__ pw,
    const float* __restrict__ W_fb, const float* __restrict__ W_r, const float* __restrict__ b_r,
    const float* __restrict__ W_z, const float* __restrict__ b_z,
    const float* __restrict__ W_ci, const float* __restrict__ b_ci,
    const float* __restrict__ W_cs, const float* __restrict__ W_sr,
    const float* __restrict__ pooled_ts, float* __restrict__ ctrl,
    float* __restrict__ bias_out, uchar* __restrict__ active)
{
  const int tid = threadIdx.x;
  if (blockIdx.x < 4) {
    __shared__ float si[256], rc[256], cn[256];
    const int b = blockIdx.x;
    const int d = tid;
    float pf = 0.f;
    for (int e2 = 0; e2 < 64; ++e2) pf += W_fb[d * 64 + e2] * pw[b * 64 + e2];
    float sid = (pooled_ts[b * 256 + d] + pf) * (1.f / 4096.f);
    si[d] = sid;
    __syncthreads();
    float ar = b_r[d], az = b_z[d], ai = b_ci[d];
    for (int k = 0; k < 256; ++k) {
      float sv = si[k];
      ar += W_r[d * 256 + k] * sv;
      az += W_z[d * 256 + k] * sv;
      ai += W_ci[d * 256 + k] * sv;
    }
    float rg = 1.f / (1.f + expf(-ar));
    float zg = 1.f / (1.f + expf(-az));
    float cold = ctrl[b * 256 + d];
    rc[d] = rg * cold;
    __syncthreads();
    float as = 0.f;
    for (int k = 0; k < 256; ++k) as += W_cs[d * 256 + k] * rc[k];
    float cand = tanhf(ai + as);
    float cnew = (1.f - zg) * cold + zg * cand;
    ctrl[b * 256 + d] = cnew;
    cn[d] = cnew;
    __syncthreads();
    if (tid < 64) {
      float bb = 0.f;
      for (int k = 0; k < 256; ++k) bb += W_sr[tid * 256 + k] * cn[k];
      bias_out[b * 64 + tid] = bb;
    }
  } else {
    // radix-select k-th smallest margin (margins >= 0 -> uint order == float order)
    __shared__ uint hist[256];
    __shared__ uint auxv[4];     // [0]=pick [1]=kknew [2]=c_lt [3]=need
    __shared__ uint eqbase[256];
    uint pfx = 0;
    uint kk = KSEL;
    for (int shift = 24; shift >= 0; shift -= 8) {
      hist[tid] = 0;
      __syncthreads();
      for (int i = tid; i < NTOK; i += 256) {
        uint u = __float_as_uint(margins[i]);
        bool match = (shift == 24) ? true : ((u >> (shift + 8)) == (pfx >> (shift + 8)));
        if (match) atomicAdd(&hist[(u >> shift) & 255u], 1u);
      }
      __syncthreads();
      if (tid == 0) {
        uint cum = 0;
        for (int bb = 0; bb < 256; ++bb) {
          uint c = hist[bb];
          if (cum + c >= kk) { auxv[0] = (uint)bb; auxv[1] = kk - cum; break; }
          cum += c;
        }
      }
      __syncthreads();
      pfx |= auxv[0] << shift;
      kk = auxv[1];
      __syncthreads();
    }
    const uint tval = pfx;
    if (tid == 0) auxv[2] = 0;
    __syncthreads();
    uint myLt = 0, myEq = 0;
    const int i0 = tid * 64;
    for (int i = i0; i < i0 + 64; ++i) {
      uint u = __float_as_uint(margins[i]);
      myLt += (u < tval) ? 1u : 0u;
      myEq += (u == tval) ? 1u : 0u;
    }
    atomicAdd(&auxv[2], myLt);
    eqbase[tid] = myEq;
    __syncthreads();
    if (tid == 0) {
      uint run = 0;
      for (int i2 = 0; i2 < 256; ++i2) { uint c = eqbase[i2]; eqbase[i2] = run; run += c; }
      auxv[3] = (uint)KSEL - auxv[2];
    }
    __syncthreads();
    uint run = eqbase[tid];
    const uint need = auxv[3];
    for (int i = i0; i < i0 + 64; ++i) {
      uint u = __float_as_uint(margins[i]);
      uchar act = 0;
      if (u < tval) act = 1;
      else if (u == tval) { act = (run < need) ? 1 : 0; run++; }
      active[i] = act;
    }
  }
}

// ---------------- launch ----------------------------------------------------
extern "C" void kernel_launch(void* const* d_in, const int* in_sizes, int n_in,
                              void* d_out, int out_size, void* d_ws, size_t ws_size,
                              hipStream_t stream) {
  const float* hidden = (const float*)d_in[0];
  const float* W_ts = (const float*)d_in[1];
  const float* b_ts = (const float*)d_in[2];
  const float* W_tr = (const float*)d_in[3];
  const float* b_tr = (const float*)d_in[4];
  const float* W_sr = (const float*)d_in[5];
  const float* W_fb = (const float*)d_in[6];
  const float* W_r  = (const float*)d_in[7];
  const float* b_r  = (const float*)d_in[8];
  const float* W_z  = (const float*)d_in[9];
  const float* b_z  = (const float*)d_in[10];
  const float* W_ci = (const float*)d_in[11];
  const float* b_ci = (const float*)d_in[12];
  const float* W_cs = (const float*)d_in[13];
  float* out = (float*)d_out;

  char* ws = (char*)d_ws;
  float* base_logits = (float*)(ws);                                   // 4 MB
  ushort_t* Wc = (ushort_t*)(ws + (4u << 20));                         // 1.25 MB
  float* margins = (float*)(ws + (4u << 20) + 1310720u);               // 64 KB
  uchar* active = (uchar*)(ws + (4u << 20) + 1310720u + 65536u);       // 16 KB
  uchar* tag    = (uchar*)(ws + (4u << 20) + 1310720u + 65536u + 16384u); // 16 KB
  float* pooled_ts = (float*)(ws + (4u << 20) + 1310720u + 65536u + 32768u);
  float* pw0   = pooled_ts + 1024;
  float* pw1   = pw0 + 256;
  float* ctrl  = pw1 + 256;     // end of contiguous zero_region (2560 floats)
  float* bias1 = ctrl + 1024;
  float* bias2 = bias1 + 256;

  prep_kernel<<<640, 256, 0, stream>>>(W_ts, W_tr, Wc, pooled_ts);
  gemm_kernel<<<256, 640, 0, stream>>>(hidden, Wc, b_ts, b_tr, base_logits, pooled_ts);
  route_kernel<<<256, 256, 0, stream>>>(0, base_logits, nullptr, nullptr, nullptr, nullptr,
                                        margins, pw0, nullptr);
  mid_kernel<<<5, 256, 0, stream>>>(margins, pw0, W_fb, W_r, b_r, W_z, b_z, W_ci, b_ci,
                                    W_cs, W_sr, pooled_ts, ctrl, bias1, active);
  route_kernel<<<256, 256, 0, stream>>>(1, base_logits, bias1, nullptr, active, tag,
                                        margins, pw1, nullptr);
  mid_kernel<<<5, 256, 0, stream>>>(margins, pw1, W_fb, W_r, b_r, W_z, b_z, W_ci, b_ci,
                                    W_cs, W_sr, pooled_ts, ctrl, bias2, active);
  route_kernel<<<256, 256, 0, stream>>>(2, base_logits, bias1, bias2, active, tag,
                                        nullptr, nullptr, out);
}

// Round 4
// 484.716 us; speedup vs baseline: 1.0752x; 1.0752x over previous
//
#include <hip/hip_runtime.h>
#include <hip/hip_bf16.h>
#include <math.h>

typedef unsigned int uint;
typedef unsigned short ushort_t;
typedef unsigned char uchar;

typedef __attribute__((ext_vector_type(4))) float f4_t;
typedef __attribute__((ext_vector_type(4))) ushort_t u16x4_t;
typedef __attribute__((ext_vector_type(4))) uint u32x4_t;
typedef __attribute__((ext_vector_type(8))) short bfrag_t;
typedef __attribute__((ext_vector_type(4))) float facc_t;

#define K_DIM 2048
#define D_DIM 256
#define E_DIM 64
#define N_DIM 320
#define S_DIM 4096
#define NTOK 16384
#define KSEL 4096

__device__ __forceinline__ ushort_t f2bf(float f) {
  uint u = __float_as_uint(f);
  uint r = u + 0x7FFFu + ((u >> 16) & 1u);  // RNE
  return (ushort_t)(r >> 16);
}

__device__ __forceinline__ float red64(float v) {
#pragma unroll
  for (int m = 32; m; m >>= 1) v += __shfl_xor(v, m, 64);
  return v;
}

// ---------------- prep: convert weights to bf16, zero accumulators ----------
__global__ __launch_bounds__(256) void prep_kernel(
    const float* __restrict__ W_ts, const float* __restrict__ W_tr,
    ushort_t* __restrict__ Wc, float* __restrict__ zero_region)
{
  int idx = blockIdx.x * 256 + threadIdx.x;       // over N_DIM*K_DIM/4 float4s
  if (idx < (N_DIM * K_DIM / 4)) {
    int n = idx >> 9;                              // / (2048/4)
    int k4 = (idx & 511) * 4;
    const float* src = (n < D_DIM) ? (W_ts + (size_t)n * K_DIM + k4)
                                   : (W_tr + (size_t)(n - D_DIM) * K_DIM + k4);
    f4_t v = *reinterpret_cast<const f4_t*>(src);
    u16x4_t h;
    h[0] = f2bf(v[0]); h[1] = f2bf(v[1]); h[2] = f2bf(v[2]); h[3] = f2bf(v[3]);
    *reinterpret_cast<u16x4_t*>(&Wc[(size_t)n * K_DIM + k4]) = h;
  }
  if (blockIdx.x == 0) {
    for (int i = threadIdx.x; i < 2560; i += 256) zero_region[i] = 0.f;
  }
}

// ---------------- fused GEMM: base_logits + pooled tanh(token_state) --------
#define BM 64
#define BK 64
#define LDK 72   // padded row stride in halfs (144 B: 16B-aligned, bank-spread)

__global__ __launch_bounds__(640) void gemm_kernel(
    const float* __restrict__ hidden, const ushort_t* __restrict__ Wc,
    const float* __restrict__ b_ts, const float* __restrict__ b_tr,
    float* __restrict__ base_logits, float* __restrict__ pooled_ts)
{
  __shared__ ushort_t Alds[BM * LDK];      //  9216 B
  __shared__ ushort_t Blds[N_DIM * LDK];   // 46080 B
  const int tid = threadIdx.x;
  const int lane = tid & 63;
  const int w = tid >> 6;        // 0..9
  const int wc = w % 5;          // N-slice of 64
  const int wrr = w / 5;         // M-slice of 32
  const int row0 = blockIdx.x * BM;
  const int lr = lane & 15;
  const int lgp = lane >> 4;

  facc_t acc[2][4];
#pragma unroll
  for (int mi = 0; mi < 2; mi++)
#pragma unroll
    for (int ni = 0; ni < 4; ni++) acc[mi][ni] = (facc_t){0.f, 0.f, 0.f, 0.f};

  for (int k0 = 0; k0 < K_DIM; k0 += BK) {
    // stage A (f32 -> bf16): 64 rows x 64 k = 1024 float4
#pragma unroll 2
    for (int idx = tid; idx < (BM * BK / 4); idx += 640) {
      int r = idx >> 4, c4 = idx & 15;
      f4_t v = *reinterpret_cast<const f4_t*>(hidden + (size_t)(row0 + r) * K_DIM + k0 + c4 * 4);
      u16x4_t h;
      h[0] = f2bf(v[0]); h[1] = f2bf(v[1]); h[2] = f2bf(v[2]); h[3] = f2bf(v[3]);
      *reinterpret_cast<u16x4_t*>(&Alds[r * LDK + c4 * 4]) = h;
    }
    // stage B (already bf16): 320 rows x 64 k = 2560 x 16B
#pragma unroll 4
    for (int idx = tid; idx < (N_DIM * BK / 8); idx += 640) {
      int r = idx >> 3, c8 = idx & 7;
      u32x4_t v = *reinterpret_cast<const u32x4_t*>(Wc + (size_t)r * K_DIM + k0 + c8 * 8);
      *reinterpret_cast<u32x4_t*>(&Blds[r * LDK + c8 * 8]) = v;
    }
    __syncthreads();
#pragma unroll
    for (int kk = 0; kk < 2; ++kk) {
      bfrag_t af[2], bfv[4];
#pragma unroll
      for (int mi = 0; mi < 2; mi++)
        af[mi] = *reinterpret_cast<const bfrag_t*>(&Alds[(wrr * 32 + mi * 16 + lr) * LDK + kk * 32 + lgp * 8]);
#pragma unroll
      for (int ni = 0; ni < 4; ni++)
        bfv[ni] = *reinterpret_cast<const bfrag_t*>(&Blds[(wc * 64 + ni * 16 + lr) * LDK + kk * 32 + lgp * 8]);
#pragma unroll
      for (int mi = 0; mi < 2; mi++)
#pragma unroll
        for (int ni = 0; ni < 4; ni++)
          acc[mi][ni] = __builtin_amdgcn_mfma_f32_16x16x32_bf16(af[mi], bfv[ni], acc[mi][ni], 0, 0, 0);
    }
    __syncthreads();
  }

  const int b = row0 >> 12;  // batch (4096 rows per batch, 64 | 4096)
  if (wc < 4) {
    // token_state columns: tanh then pool (sum over this wave's 32 rows)
#pragma unroll
    for (int ni = 0; ni < 4; ni++) {
      const int col = wc * 64 + ni * 16 + lr;
      const float bias = b_ts[col];
      float psum = 0.f;
#pragma unroll
      for (int mi = 0; mi < 2; mi++)
#pragma unroll
        for (int j = 0; j < 4; j++)
          psum += tanhf(acc[mi][ni][j] + bias);
      psum += __shfl_xor(psum, 16, 64);
      psum += __shfl_xor(psum, 32, 64);
      if (lgp == 0) atomicAdd(&pooled_ts[b * D_DIM + col], psum);
    }
  } else {
    // base logit columns (wc == 4 -> cols 256..319)
#pragma unroll
    for (int ni = 0; ni < 4; ni++) {
      const int e = ni * 16 + lr;
      const float bias = b_tr[e];
#pragma unroll
      for (int mi = 0; mi < 2; mi++)
#pragma unroll
        for (int j = 0; j < 4; j++) {
          const int row = row0 + wrr * 32 + mi * 16 + lgp * 4 + j;
          base_logits[(size_t)row * E_DIM + e] = acc[mi][ni][j] + bias;
        }
    }
  }
}

// ---------------- per-round softmax / margins / pooling ---------------------
__global__ __launch_bounds__(256) void route_kernel(
    int round,
    const float* __restrict__ base_logits,
    const float* __restrict__ bias1, const float* __restrict__ bias2,
    const uchar* __restrict__ active, uchar* __restrict__ tag,
    float* __restrict__ margins, float* __restrict__ pw_out,
    float* __restrict__ out)
{
  __shared__ float sm[4][64];
  const int tid = threadIdx.x;
  const int lane = tid & 63;
  const int wid = tid >> 6;
  const int b = blockIdx.x >> 6;   // 64 tokens/block, 4096 tokens/batch
  float pacc = 0.f;
  for (int i = 0; i < 16; ++i) {
    const int t = blockIdx.x * 64 + wid * 16 + i;
    float lgt = base_logits[(size_t)t * E_DIM + lane];
    if (round == 1) {
      uchar a = active[t];
      if (a) lgt += bias1[b * E_DIM + lane];
      if (lane == 0) tag[t] = a;
    } else if (round == 2) {
      uchar a = active[t];
      if (a) lgt += bias2[b * E_DIM + lane];
      else if (tag[t]) lgt += bias1[b * E_DIM + lane];
    }
    float m1 = lgt;
#pragma unroll
    for (int mm = 32; mm; mm >>= 1) m1 = fmaxf(m1, __shfl_xor(m1, mm, 64));
    float e = expf(lgt - m1);
    float s = e;
#pragma unroll
    for (int mm = 32; mm; mm >>= 1) s += __shfl_xor(s, mm, 64);
    if (round == 2) {
      out[(size_t)t * E_DIM + lane] = e / s;
    } else {
      pacc += e / s;
      unsigned long long bal = __ballot(lgt == m1);
      int first = __ffsll((unsigned long long)bal) - 1;
      float l2 = (lane == first) ? -__builtin_inff() : lgt;
#pragma unroll
      for (int mm = 32; mm; mm >>= 1) l2 = fmaxf(l2, __shfl_xor(l2, mm, 64));
      if (lane == 0) margins[t] = (1.f - expf(l2 - m1)) / s;   // top1-top2 of weights
    }
  }
  if (round != 2) {
    sm[wid][lane] = pacc;
    __syncthreads();
    if (wid == 0) {
      float v = sm[0][lane] + sm[1][lane] + sm[2][lane] + sm[3][lane];
      atomicAdd(&pw_out[b * E_DIM + lane], v);
    }
  }
}

// ---------------- mid: GRU (blocks 0..3) + k-smallest select (block 4) ------
// 1024 threads/block. GRU: wave-per-row coalesced dot products (float4 row
// reads + shfl reduce) — replaces the rolled 256-iteration scalar loops that
// made this kernel latency-bound (105us). Select: vectorized uint4 loads,
// ballot-aggregated histogram, wave-scan tie ranking.
__global__ __launch_bounds__(1024) void mid_kernel(
    const float* __restrict__ margins,
    const float* __restrict__ pw,
    const float* __restrict__ W_fb, const float* __restrict__ W_r, const float* __restrict__ b_r,
    const float* __restrict__ W_z, const float* __restrict__ b_z,
    const float* __restrict__ W_ci, const float* __restrict__ b_ci,
    const float* __restrict__ W_cs, const float* __restrict__ W_sr,
    const float* __restrict__ pooled_ts, float* __restrict__ ctrl,
    float* __restrict__ bias_out, uchar* __restrict__ active)
{
  const int tid = threadIdx.x;
  const int lane = tid & 63;
  const int wid = tid >> 6;      // 0..15
  if (blockIdx.x < 4) {
    __shared__ float si[256], rcs[256], zgs[256], ais[256], cns[256];
    const int b = blockIdx.x;
    const float pwv = pw[b * 64 + lane];
    // stage 0: si[d] = (pooled_ts + W_fb @ pw) / 4096
    for (int r = wid; r < 256; r += 16) {
      float v = W_fb[r * 64 + lane] * pwv;
      v = red64(v);
      if (lane == 0) si[r] = (pooled_ts[b * 256 + r] + v) * (1.f / 4096.f);
    }
    __syncthreads();
    // stage 1: three 256x256 matvecs (W_r, W_z, W_ci) @ si
    for (int t = wid; t < 768; t += 16) {
      const int m = t >> 8, r = t & 255;
      const float* Wm = (m == 0) ? W_r : (m == 1) ? W_z : W_ci;
      f4_t wv = *reinterpret_cast<const f4_t*>(&Wm[r * 256 + lane * 4]);
      f4_t xv = *reinterpret_cast<const f4_t*>(&si[lane * 4]);
      float v = wv[0] * xv[0] + wv[1] * xv[1] + wv[2] * xv[2] + wv[3] * xv[3];
      v = red64(v);
      if (lane == 0) {
        if (m == 0) {
          float rg = 1.f / (1.f + expf(-(v + b_r[r])));
          rcs[r] = rg * ctrl[b * 256 + r];
        } else if (m == 1) {
          zgs[r] = 1.f / (1.f + expf(-(v + b_z[r])));
        } else {
          ais[r] = v + b_ci[r];
        }
      }
    }
    __syncthreads();
    // stage 2: W_cs @ rc, then GRU combine
    for (int r = wid; r < 256; r += 16) {
      f4_t wv = *reinterpret_cast<const f4_t*>(&W_cs[r * 256 + lane * 4]);
      f4_t xv = *reinterpret_cast<const f4_t*>(&rcs[lane * 4]);
      float v = wv[0] * xv[0] + wv[1] * xv[1] + wv[2] * xv[2] + wv[3] * xv[3];
      v = red64(v);
      if (lane == 0) {
        float cold = ctrl[b * 256 + r];
        float zg = zgs[r];
        float cand = tanhf(ais[r] + v);
        float cnew = (1.f - zg) * cold + zg * cand;
        ctrl[b * 256 + r] = cnew;
        cns[r] = cnew;
      }
    }
    __syncthreads();
    // stage 3: route bias = W_sr @ ctrl  (64 rows)
    for (int r = wid; r < 64; r += 16) {
      f4_t wv = *reinterpret_cast<const f4_t*>(&W_sr[r * 256 + lane * 4]);
      f4_t xv = *reinterpret_cast<const f4_t*>(&cns[lane * 4]);
      float v = wv[0] * xv[0] + wv[1] * xv[1] + wv[2] * xv[2] + wv[3] * xv[3];
      v = red64(v);
      if (lane == 0) bias_out[b * 64 + r] = v;
    }
  } else {
    // exact k-smallest radix select (margins >= 0 -> uint order == float order)
    __shared__ uint hist[256];
    __shared__ uint aux2[4];     // [0]=pick [1]=kknew [2]=c_lt [3]=need
    __shared__ uint wsum[16];
    const u32x4_t* mv = reinterpret_cast<const u32x4_t*>(margins);
    uint pfx = 0, kk = KSEL;
    for (int shift = 24; shift >= 0; shift -= 8) {
      if (tid < 256) hist[tid] = 0;
      __syncthreads();
#pragma unroll
      for (int p = 0; p < 4; ++p) {
        u32x4_t v = mv[p * 1024 + tid];
#pragma unroll
        for (int e = 0; e < 4; ++e) {
          uint u = v[e];
          bool ok = (shift == 24) || ((u >> (shift + 8)) == (pfx >> (shift + 8)));
          uint bin = (u >> shift) & 255u;
          unsigned long long m = __ballot(ok);
#pragma unroll
          for (int bit = 0; bit < 8; ++bit) {
            unsigned long long bb = __ballot(ok && ((bin >> bit) & 1u));
            m &= ((bin >> bit) & 1u) ? bb : ~bb;
          }
          if (ok && (__ffsll(m) - 1) == lane) atomicAdd(&hist[bin], (uint)__popcll(m));
        }
      }
      __syncthreads();
      if (tid == 0) {
        uint cum = 0;
        for (int bb2 = 0; bb2 < 256; ++bb2) {
          uint c = hist[bb2];
          if (cum + c >= kk) { aux2[0] = (uint)bb2; aux2[1] = kk - cum; break; }
          cum += c;
        }
        aux2[2] = 0;
      }
      __syncthreads();
      pfx |= aux2[0] << shift;
      kk = aux2[1];
      __syncthreads();
    }
    const uint tval = pfx;
    // count lt / stable rank of equals; each thread owns 16 contiguous elems
    uint myLt = 0, myEq = 0;
    u32x4_t loc[4];
#pragma unroll
    for (int q = 0; q < 4; ++q) {
      loc[q] = mv[tid * 4 + q];
#pragma unroll
      for (int e = 0; e < 4; ++e) {
        uint u = loc[q][e];
        myLt += (u < tval) ? 1u : 0u;
        myEq += (u == tval) ? 1u : 0u;
      }
    }
    uint lt = myLt;
#pragma unroll
    for (int m = 32; m; m >>= 1) lt += __shfl_xor(lt, m, 64);
    if (lane == 0) atomicAdd(&aux2[2], lt);
    uint x = myEq;
#pragma unroll
    for (int d = 1; d < 64; d <<= 1) {
      uint y = __shfl_up(x, d, 64);
      if (lane >= d) x += y;
    }
    if (lane == 63) wsum[wid] = x;
    __syncthreads();
    if (tid == 0) {
      uint run = 0;
      for (int w2 = 0; w2 < 16; ++w2) { uint c = wsum[w2]; wsum[w2] = run; run += c; }
      aux2[3] = (uint)KSEL - aux2[2];
    }
    __syncthreads();
    uint pos = wsum[wid] + (x - myEq);
    const uint need = aux2[3];
#pragma unroll
    for (int q = 0; q < 4; ++q) {
#pragma unroll
      for (int e = 0; e < 4; ++e) {
        uint u = loc[q][e];
        uchar a = 0;
        if (u < tval) a = 1;
        else if (u == tval) { a = (pos < need) ? 1 : 0; pos++; }
        active[tid * 16 + q * 4 + e] = a;
      }
    }
  }
}

// ---------------- launch ----------------------------------------------------
extern "C" void kernel_launch(void* const* d_in, const int* in_sizes, int n_in,
                              void* d_out, int out_size, void* d_ws, size_t ws_size,
                              hipStream_t stream) {
  const float* hidden = (const float*)d_in[0];
  const float* W_ts = (const float*)d_in[1];
  const float* b_ts = (const float*)d_in[2];
  const float* W_tr = (const float*)d_in[3];
  const float* b_tr = (const float*)d_in[4];
  const float* W_sr = (const float*)d_in[5];
  const float* W_fb = (const float*)d_in[6];
  const float* W_r  = (const float*)d_in[7];
  const float* b_r  = (const float*)d_in[8];
  const float* W_z  = (const float*)d_in[9];
  const float* b_z  = (const float*)d_in[10];
  const float* W_ci = (const float*)d_in[11];
  const float* b_ci = (const float*)d_in[12];
  const float* W_cs = (const float*)d_in[13];
  float* out = (float*)d_out;

  char* ws = (char*)d_ws;
  float* base_logits = (float*)(ws);                                   // 4 MB
  ushort_t* Wc = (ushort_t*)(ws + (4u << 20));                         // 1.25 MB
  float* margins = (float*)(ws + (4u << 20) + 1310720u);               // 64 KB
  uchar* active = (uchar*)(ws + (4u << 20) + 1310720u + 65536u);       // 16 KB
  uchar* tag    = (uchar*)(ws + (4u << 20) + 1310720u + 65536u + 16384u); // 16 KB
  float* pooled_ts = (float*)(ws + (4u << 20) + 1310720u + 65536u + 32768u);
  float* pw0   = pooled_ts + 1024;
  float* pw1   = pw0 + 256;
  float* ctrl  = pw1 + 256;     // end of contiguous zero_region (2560 floats)
  float* bias1 = ctrl + 1024;
  float* bias2 = bias1 + 256;

  prep_kernel<<<640, 256, 0, stream>>>(W_ts, W_tr, Wc, pooled_ts);
  gemm_kernel<<<256, 640, 0, stream>>>(hidden, Wc, b_ts, b_tr, base_logits, pooled_ts);
  route_kernel<<<256, 256, 0, stream>>>(0, base_logits, nullptr, nullptr, nullptr, nullptr,
                                        margins, pw0, nullptr);
  mid_kernel<<<5, 1024, 0, stream>>>(margins, pw0, W_fb, W_r, b_r, W_z, b_z, W_ci, b_ci,
                                     W_cs, W_sr, pooled_ts, ctrl, bias1, active);
  route_kernel<<<256, 256, 0, stream>>>(1, base_logits, bias1, nullptr, active, tag,
                                        margins, pw1, nullptr);
  mid_kernel<<<5, 1024, 0, stream>>>(margins, pw1, W_fb, W_r, b_r, W_z, b_z, W_ci, b_ci,
                                     W_cs, W_sr, pooled_ts, ctrl, bias2, active);
  route_kernel<<<256, 256, 0, stream>>>(2, base_logits, bias1, bias2, active, tag,
                                        nullptr, nullptr, out);
}

// Round 5
// 457.062 us; speedup vs baseline: 1.1403x; 1.0605x over previous
//
#include <hip/hip_runtime.h>
#include <hip/hip_bf16.h>
#include <math.h>

typedef unsigned int uint;
typedef unsigned short ushort_t;
typedef unsigned char uchar;

typedef __attribute__((ext_vector_type(4))) float f4_t;
typedef __attribute__((ext_vector_type(4))) ushort_t u16x4_t;
typedef __attribute__((ext_vector_type(4))) uint u32x4_t;
typedef __attribute__((ext_vector_type(8))) short bfrag_t;
typedef __attribute__((ext_vector_type(4))) float facc_t;

#define K_DIM 2048
#define D_DIM 256
#define E_DIM 64
#define N_DIM 320
#define S_DIM 4096
#define NTOK 16384
#define KSEL 4096

__device__ __forceinline__ ushort_t f2bf(float f) {
  uint u = __float_as_uint(f);
  uint r = u + 0x7FFFu + ((u >> 16) & 1u);  // RNE
  return (ushort_t)(r >> 16);
}

__device__ __forceinline__ float red64(float v) {
#pragma unroll
  for (int m = 32; m; m >>= 1) v += __shfl_xor(v, m, 64);
  return v;
}

// ---------------- prep: convert weights to bf16, zero accumulators ----------
__global__ __launch_bounds__(256) void prep_kernel(
    const float* __restrict__ W_ts, const float* __restrict__ W_tr,
    ushort_t* __restrict__ Wc, float* __restrict__ zero_region)
{
  int idx = blockIdx.x * 256 + threadIdx.x;       // over N_DIM*K_DIM/4 float4s
  if (idx < (N_DIM * K_DIM / 4)) {
    int n = idx >> 9;                              // / (2048/4)
    int k4 = (idx & 511) * 4;
    const float* src = (n < D_DIM) ? (W_ts + (size_t)n * K_DIM + k4)
                                   : (W_tr + (size_t)(n - D_DIM) * K_DIM + k4);
    f4_t v = *reinterpret_cast<const f4_t*>(src);
    u16x4_t h;
    h[0] = f2bf(v[0]); h[1] = f2bf(v[1]); h[2] = f2bf(v[2]); h[3] = f2bf(v[3]);
    *reinterpret_cast<u16x4_t*>(&Wc[(size_t)n * K_DIM + k4]) = h;
  }
  if (blockIdx.x == 0) {
    for (int i = threadIdx.x; i < 2560; i += 256) zero_region[i] = 0.f;
  }
}

// ---------------- fused GEMM: base_logits + pooled tanh(token_state) --------
// BM=32, 512 blocks, 320 threads (5 waves), LDS ~50.7KB -> 3 blocks/CU.
// Cross-block overlap hides the per-K-step staging drain (1-block/CU version
// measured latency-bound: Mfma 8%, VALU 9%, HBM 9%, occ 27%).
#define BM 32
#define BK 64
#define LDK 72   // padded row stride in halfs (144 B: 16B-aligned, bank-spread)

__global__ __launch_bounds__(320) void gemm_kernel(
    const float* __restrict__ hidden, const ushort_t* __restrict__ Wc,
    const float* __restrict__ b_ts, const float* __restrict__ b_tr,
    float* __restrict__ base_logits, float* __restrict__ pooled_ts)
{
  __shared__ ushort_t Alds[BM * LDK];      //  4608 B
  __shared__ ushort_t Blds[N_DIM * LDK];   // 46080 B
  const int tid = threadIdx.x;
  const int lane = tid & 63;
  const int wc = tid >> 6;       // 0..4 : N-slice of 64
  const int row0 = blockIdx.x * BM;
  const int lr = lane & 15;
  const int lgp = lane >> 4;

  facc_t acc[2][4];
#pragma unroll
  for (int mi = 0; mi < 2; mi++)
#pragma unroll
    for (int ni = 0; ni < 4; ni++) acc[mi][ni] = (facc_t){0.f, 0.f, 0.f, 0.f};

  for (int k0 = 0; k0 < K_DIM; k0 += BK) {
    // stage A (f32 -> bf16): 32 rows x 64 k = 512 float4. HBM loads issued
    // FIRST so their ~900cy latency overlaps B's L2 staging below.
    f4_t va[2];
    int na = 0;
#pragma unroll 2
    for (int idx = tid; idx < (BM * BK / 4); idx += 320) {
      va[na++] = *reinterpret_cast<const f4_t*>(
          hidden + (size_t)(row0 + (idx >> 4)) * K_DIM + k0 + (idx & 15) * 4);
    }
    // stage B (already bf16, L2-resident): 320 rows x 64 k = 2560 x 16B
#pragma unroll 8
    for (int idx = tid; idx < (N_DIM * BK / 8); idx += 320) {
      int r = idx >> 3, c8 = idx & 7;
      u32x4_t v = *reinterpret_cast<const u32x4_t*>(Wc + (size_t)r * K_DIM + k0 + c8 * 8);
      *reinterpret_cast<u32x4_t*>(&Blds[r * LDK + c8 * 8]) = v;
    }
    na = 0;
#pragma unroll 2
    for (int idx = tid; idx < (BM * BK / 4); idx += 320) {
      f4_t v = va[na++];
      u16x4_t h;
      h[0] = f2bf(v[0]); h[1] = f2bf(v[1]); h[2] = f2bf(v[2]); h[3] = f2bf(v[3]);
      *reinterpret_cast<u16x4_t*>(&Alds[(idx >> 4) * LDK + (idx & 15) * 4]) = h;
    }
    __syncthreads();
#pragma unroll
    for (int kk = 0; kk < 2; ++kk) {
      bfrag_t af[2], bfv[4];
#pragma unroll
      for (int mi = 0; mi < 2; mi++)
        af[mi] = *reinterpret_cast<const bfrag_t*>(&Alds[(mi * 16 + lr) * LDK + kk * 32 + lgp * 8]);
#pragma unroll
      for (int ni = 0; ni < 4; ni++)
        bfv[ni] = *reinterpret_cast<const bfrag_t*>(&Blds[(wc * 64 + ni * 16 + lr) * LDK + kk * 32 + lgp * 8]);
#pragma unroll
      for (int mi = 0; mi < 2; mi++)
#pragma unroll
        for (int ni = 0; ni < 4; ni++)
          acc[mi][ni] = __builtin_amdgcn_mfma_f32_16x16x32_bf16(af[mi], bfv[ni], acc[mi][ni], 0, 0, 0);
    }
    __syncthreads();
  }

  const int b = row0 >> 12;  // batch (4096 rows per batch, 32 | 4096)
  if (wc < 4) {
    // token_state columns: tanh then pool (sum over the block's 32 rows)
#pragma unroll
    for (int ni = 0; ni < 4; ni++) {
      const int col = wc * 64 + ni * 16 + lr;
      const float bias = b_ts[col];
      float psum = 0.f;
#pragma unroll
      for (int mi = 0; mi < 2; mi++)
#pragma unroll
        for (int j = 0; j < 4; j++)
          psum += tanhf(acc[mi][ni][j] + bias);
      psum += __shfl_xor(psum, 16, 64);
      psum += __shfl_xor(psum, 32, 64);
      if (lgp == 0) atomicAdd(&pooled_ts[b * D_DIM + col], psum);
    }
  } else {
    // base logit columns (wc == 4 -> cols 256..319)
#pragma unroll
    for (int ni = 0; ni < 4; ni++) {
      const int e = ni * 16 + lr;
      const float bias = b_tr[e];
#pragma unroll
      for (int mi = 0; mi < 2; mi++)
#pragma unroll
        for (int j = 0; j < 4; j++) {
          const int row = row0 + mi * 16 + lgp * 4 + j;
          base_logits[(size_t)row * E_DIM + e] = acc[mi][ni][j] + bias;
        }
    }
  }
}

// ---------------- per-round softmax / margins / pooling ---------------------
// 1024 blocks x 256 thr (4 blocks/CU), 4 tokens/wave, all loads batched up
// front (previous 1-block/CU 16-serial-load version was latency-bound).
__global__ __launch_bounds__(256) void route_kernel(
    int round,
    const float* __restrict__ base_logits,
    const float* __restrict__ bias1, const float* __restrict__ bias2,
    const uchar* __restrict__ active, uchar* __restrict__ tag,
    float* __restrict__ margins, float* __restrict__ pw_out,
    float* __restrict__ out)
{
  __shared__ float sm[4][64];
  const int tid = threadIdx.x;
  const int lane = tid & 63;
  const int wid = tid >> 6;
  const int b = blockIdx.x >> 8;   // 16 tokens/block, 256 blocks/batch
  const int t0 = blockIdx.x * 16 + wid * 4;

  float bv1 = 0.f, bv2 = 0.f;
  if (round >= 1) bv1 = bias1[b * E_DIM + lane];
  if (round == 2) bv2 = bias2[b * E_DIM + lane];

  float lg[4];
#pragma unroll
  for (int i = 0; i < 4; ++i)
    lg[i] = base_logits[(size_t)(t0 + i) * E_DIM + lane];

  if (round == 1) {
    uchar a[4];
#pragma unroll
    for (int i = 0; i < 4; ++i) a[i] = active[t0 + i];
#pragma unroll
    for (int i = 0; i < 4; ++i) {
      if (lane == 0) tag[t0 + i] = a[i];
      if (a[i]) lg[i] += bv1;
    }
  } else if (round == 2) {
    uchar a[4], tg[4];
#pragma unroll
    for (int i = 0; i < 4; ++i) { a[i] = active[t0 + i]; tg[i] = tag[t0 + i]; }
#pragma unroll
    for (int i = 0; i < 4; ++i)
      lg[i] += a[i] ? bv2 : (tg[i] ? bv1 : 0.f);
  }

  float pacc = 0.f;
#pragma unroll
  for (int i = 0; i < 4; ++i) {
    const float lgt = lg[i];
    float m1 = lgt;
#pragma unroll
    for (int mm = 32; mm; mm >>= 1) m1 = fmaxf(m1, __shfl_xor(m1, mm, 64));
    float e = expf(lgt - m1);
    float s = e;
#pragma unroll
    for (int mm = 32; mm; mm >>= 1) s += __shfl_xor(s, mm, 64);
    if (round == 2) {
      out[(size_t)(t0 + i) * E_DIM + lane] = e / s;
    } else {
      pacc += e / s;
      unsigned long long bal = __ballot(lgt == m1);
      int first = __ffsll((unsigned long long)bal) - 1;
      float l2 = (lane == first) ? -__builtin_inff() : lgt;
#pragma unroll
      for (int mm = 32; mm; mm >>= 1) l2 = fmaxf(l2, __shfl_xor(l2, mm, 64));
      if (lane == 0) margins[t0 + i] = (1.f - expf(l2 - m1)) / s;  // top1-top2 of weights
    }
  }
  if (round != 2) {
    sm[wid][lane] = pacc;
    __syncthreads();
    if (wid == 0) {
      float v = sm[0][lane] + sm[1][lane] + sm[2][lane] + sm[3][lane];
      atomicAdd(&pw_out[b * E_DIM + lane], v);
    }
  }
}

// ---------------- mid: GRU (blocks 0..3) + k-smallest select (block 4) ------
__global__ __launch_bounds__(1024) void mid_kernel(
    const float* __restrict__ margins,
    const float* __restrict__ pw,
    const float* __restrict__ W_fb, const float* __restrict__ W_r, const float* __restrict__ b_r,
    const float* __restrict__ W_z, const float* __restrict__ b_z,
    const float* __restrict__ W_ci, const float* __restrict__ b_ci,
    const float* __restrict__ W_cs, const float* __restrict__ W_sr,
    const float* __restrict__ pooled_ts, float* __restrict__ ctrl,
    float* __restrict__ bias_out, uchar* __restrict__ active)
{
  const int tid = threadIdx.x;
  const int lane = tid & 63;
  const int wid = tid >> 6;      // 0..15
  if (blockIdx.x < 4) {
    __shared__ float si[256], rcs[256], zgs[256], ais[256], cns[256];
    const int b = blockIdx.x;
    const float pwv = pw[b * 64 + lane];
    // stage 0: si[d] = (pooled_ts + W_fb @ pw) / 4096
    for (int r = wid; r < 256; r += 16) {
      float v = W_fb[r * 64 + lane] * pwv;
      v = red64(v);
      if (lane == 0) si[r] = (pooled_ts[b * 256 + r] + v) * (1.f / 4096.f);
    }
    __syncthreads();
    // stage 1: three 256x256 matvecs (W_r, W_z, W_ci) @ si
    for (int t = wid; t < 768; t += 16) {
      const int m = t >> 8, r = t & 255;
      const float* Wm = (m == 0) ? W_r : (m == 1) ? W_z : W_ci;
      f4_t wv = *reinterpret_cast<const f4_t*>(&Wm[r * 256 + lane * 4]);
      f4_t xv = *reinterpret_cast<const f4_t*>(&si[lane * 4]);
      float v = wv[0] * xv[0] + wv[1] * xv[1] + wv[2] * xv[2] + wv[3] * xv[3];
      v = red64(v);
      if (lane == 0) {
        if (m == 0) {
          float rg = 1.f / (1.f + expf(-(v + b_r[r])));
          rcs[r] = rg * ctrl[b * 256 + r];
        } else if (m == 1) {
          zgs[r] = 1.f / (1.f + expf(-(v + b_z[r])));
        } else {
          ais[r] = v + b_ci[r];
        }
      }
    }
    __syncthreads();
    // stage 2: W_cs @ rc, then GRU combine
    for (int r = wid; r < 256; r += 16) {
      f4_t wv = *reinterpret_cast<const f4_t*>(&W_cs[r * 256 + lane * 4]);
      f4_t xv = *reinterpret_cast<const f4_t*>(&rcs[lane * 4]);
      float v = wv[0] * xv[0] + wv[1] * xv[1] + wv[2] * xv[2] + wv[3] * xv[3];
      v = red64(v);
      if (lane == 0) {
        float cold = ctrl[b * 256 + r];
        float zg = zgs[r];
        float cand = tanhf(ais[r] + v);
        float cnew = (1.f - zg) * cold + zg * cand;
        ctrl[b * 256 + r] = cnew;
        cns[r] = cnew;
      }
    }
    __syncthreads();
    // stage 3: route bias = W_sr @ ctrl  (64 rows)
    for (int r = wid; r < 64; r += 16) {
      f4_t wv = *reinterpret_cast<const f4_t*>(&W_sr[r * 256 + lane * 4]);
      f4_t xv = *reinterpret_cast<const f4_t*>(&cns[lane * 4]);
      float v = wv[0] * xv[0] + wv[1] * xv[1] + wv[2] * xv[2] + wv[3] * xv[3];
      v = red64(v);
      if (lane == 0) bias_out[b * 64 + r] = v;
    }
  } else {
    // exact k-smallest radix select (margins >= 0 -> uint order == float order)
    __shared__ uint hist[256];
    __shared__ uint aux2[4];     // [0]=pick [1]=kknew [2]=c_lt [3]=need
    __shared__ uint wsum[16];
    const u32x4_t* mv = reinterpret_cast<const u32x4_t*>(margins);
    uint pfx = 0, kk = KSEL;
    for (int shift = 24; shift >= 0; shift -= 8) {
      if (tid < 256) hist[tid] = 0;
      __syncthreads();
#pragma unroll
      for (int p = 0; p < 4; ++p) {
        u32x4_t v = mv[p * 1024 + tid];
#pragma unroll
        for (int e = 0; e < 4; ++e) {
          uint u = v[e];
          bool ok = (shift == 24) || ((u >> (shift + 8)) == (pfx >> (shift + 8)));
          uint bin = (u >> shift) & 255u;
          unsigned long long m = __ballot(ok);
#pragma unroll
          for (int bit = 0; bit < 8; ++bit) {
            unsigned long long bb = __ballot(ok && ((bin >> bit) & 1u));
            m &= ((bin >> bit) & 1u) ? bb : ~bb;
          }
          if (ok && (__ffsll(m) - 1) == lane) atomicAdd(&hist[bin], (uint)__popcll(m));
        }
      }
      __syncthreads();
      if (tid == 0) {
        uint cum = 0;
        for (int bb2 = 0; bb2 < 256; ++bb2) {
          uint c = hist[bb2];
          if (cum + c >= kk) { aux2[0] = (uint)bb2; aux2[1] = kk - cum; break; }
          cum += c;
        }
        aux2[2] = 0;
      }
      __syncthreads();
      pfx |= aux2[0] << shift;
      kk = aux2[1];
      __syncthreads();
    }
    const uint tval = pfx;
    // count lt / stable rank of equals; each thread owns 16 contiguous elems
    uint myLt = 0, myEq = 0;
    u32x4_t loc[4];
#pragma unroll
    for (int q = 0; q < 4; ++q) {
      loc[q] = mv[tid * 4 + q];
#pragma unroll
      for (int e = 0; e < 4; ++e) {
        uint u = loc[q][e];
        myLt += (u < tval) ? 1u : 0u;
        myEq += (u == tval) ? 1u : 0u;
      }
    }
    uint lt = myLt;
#pragma unroll
    for (int m = 32; m; m >>= 1) lt += __shfl_xor(lt, m, 64);
    if (lane == 0) atomicAdd(&aux2[2], lt);
    uint x = myEq;
#pragma unroll
    for (int d = 1; d < 64; d <<= 1) {
      uint y = __shfl_up(x, d, 64);
      if (lane >= d) x += y;
    }
    if (lane == 63) wsum[wid] = x;
    __syncthreads();
    if (tid == 0) {
      uint run = 0;
      for (int w2 = 0; w2 < 16; ++w2) { uint c = wsum[w2]; wsum[w2] = run; run += c; }
      aux2[3] = (uint)KSEL - aux2[2];
    }
    __syncthreads();
    uint pos = wsum[wid] + (x - myEq);
    const uint need = aux2[3];
#pragma unroll
    for (int q = 0; q < 4; ++q) {
#pragma unroll
      for (int e = 0; e < 4; ++e) {
        uint u = loc[q][e];
        uchar a = 0;
        if (u < tval) a = 1;
        else if (u == tval) { a = (pos < need) ? 1 : 0; pos++; }
        active[tid * 16 + q * 4 + e] = a;
      }
    }
  }
}

// ---------------- launch ----------------------------------------------------
extern "C" void kernel_launch(void* const* d_in, const int* in_sizes, int n_in,
                              void* d_out, int out_size, void* d_ws, size_t ws_size,
                              hipStream_t stream) {
  const float* hidden = (const float*)d_in[0];
  const float* W_ts = (const float*)d_in[1];
  const float* b_ts = (const float*)d_in[2];
  const float* W_tr = (const float*)d_in[3];
  const float* b_tr = (const float*)d_in[4];
  const float* W_sr = (const float*)d_in[5];
  const float* W_fb = (const float*)d_in[6];
  const float* W_r  = (const float*)d_in[7];
  const float* b_r  = (const float*)d_in[8];
  const float* W_z  = (const float*)d_in[9];
  const float* b_z  = (const float*)d_in[10];
  const float* W_ci = (const float*)d_in[11];
  const float* b_ci = (const float*)d_in[12];
  const float* W_cs = (const float*)d_in[13];
  float* out = (float*)d_out;

  char* ws = (char*)d_ws;
  float* base_logits = (float*)(ws);                                   // 4 MB
  ushort_t* Wc = (ushort_t*)(ws + (4u << 20));                         // 1.25 MB
  float* margins = (float*)(ws + (4u << 20) + 1310720u);               // 64 KB
  uchar* active = (uchar*)(ws + (4u << 20) + 1310720u + 65536u);       // 16 KB
  uchar* tag    = (uchar*)(ws + (4u << 20) + 1310720u + 65536u + 16384u); // 16 KB
  float* pooled_ts = (float*)(ws + (4u << 20) + 1310720u + 65536u + 32768u);
  float* pw0   = pooled_ts + 1024;
  float* pw1   = pw0 + 256;
  float* ctrl  = pw1 + 256;     // end of contiguous zero_region (2560 floats)
  float* bias1 = ctrl + 1024;
  float* bias2 = bias1 + 256;

  prep_kernel<<<640, 256, 0, stream>>>(W_ts, W_tr, Wc, pooled_ts);
  gemm_kernel<<<512, 320, 0, stream>>>(hidden, Wc, b_ts, b_tr, base_logits, pooled_ts);
  route_kernel<<<1024, 256, 0, stream>>>(0, base_logits, nullptr, nullptr, nullptr, nullptr,
                                         margins, pw0, nullptr);
  mid_kernel<<<5, 1024, 0, stream>>>(margins, pw0, W_fb, W_r, b_r, W_z, b_z, W_ci, b_ci,
                                     W_cs, W_sr, pooled_ts, ctrl, bias1, active);
  route_kernel<<<1024, 256, 0, stream>>>(1, base_logits, bias1, nullptr, active, tag,
                                         margins, pw1, nullptr);
  mid_kernel<<<5, 1024, 0, stream>>>(margins, pw1, W_fb, W_r, b_r, W_z, b_z, W_ci, b_ci,
                                     W_cs, W_sr, pooled_ts, ctrl, bias2, active);
  route_kernel<<<1024, 256, 0, stream>>>(2, base_logits, bias1, bias2, active, tag,
                                         nullptr, nullptr, out);
}

// Round 6
// 400.622 us; speedup vs baseline: 1.3009x; 1.1409x over previous
//
#include <hip/hip_runtime.h>
#include <hip/hip_bf16.h>
#include <math.h>

typedef unsigned int uint;
typedef unsigned short ushort_t;
typedef unsigned char uchar;

typedef __attribute__((ext_vector_type(4))) float f4_t;
typedef __attribute__((ext_vector_type(4))) ushort_t u16x4_t;
typedef __attribute__((ext_vector_type(4))) uint u32x4_t;
typedef __attribute__((ext_vector_type(8))) short bfrag_t;
typedef __attribute__((ext_vector_type(4))) float facc_t;

#define K_DIM 2048
#define D_DIM 256
#define E_DIM 64
#define N_DIM 320
#define S_DIM 4096
#define NTOK 16384
#define KSEL 4096

__device__ __forceinline__ ushort_t f2bf(float f) {
  uint u = __float_as_uint(f);
  uint r = u + 0x7FFFu + ((u >> 16) & 1u);  // RNE
  return (ushort_t)(r >> 16);
}

__device__ __forceinline__ float red64(float v) {
#pragma unroll
  for (int m = 32; m; m >>= 1) v += __shfl_xor(v, m, 64);
  return v;
}

// ---------------- prep: convert weights to bf16, zero accumulators ----------
__global__ __launch_bounds__(256) void prep_kernel(
    const float* __restrict__ W_ts, const float* __restrict__ W_tr,
    ushort_t* __restrict__ Wc, float* __restrict__ zero_region)
{
  int idx = blockIdx.x * 256 + threadIdx.x;       // over N_DIM*K_DIM/4 float4s
  if (idx < (N_DIM * K_DIM / 4)) {
    int n = idx >> 9;                              // / (2048/4)
    int k4 = (idx & 511) * 4;
    const float* src = (n < D_DIM) ? (W_ts + (size_t)n * K_DIM + k4)
                                   : (W_tr + (size_t)(n - D_DIM) * K_DIM + k4);
    f4_t v = *reinterpret_cast<const f4_t*>(src);
    u16x4_t h;
    h[0] = f2bf(v[0]); h[1] = f2bf(v[1]); h[2] = f2bf(v[2]); h[3] = f2bf(v[3]);
    *reinterpret_cast<u16x4_t*>(&Wc[(size_t)n * K_DIM + k4]) = h;
  }
  if (blockIdx.x == 0) {
    for (int i = threadIdx.x; i < 2560; i += 256) zero_region[i] = 0.f;
  }
}

// ---------------- fused GEMM: base_logits + pooled tanh(token_state) --------
// BM=64, 640 thr (10 waves = 2M x 5N). T14 issue-early/write-late register
// prefetch: tile t+1's global loads are issued before tile t's MFMA phase so
// each K-step pays issue cost, not a serialized L2/HBM round trip (R5 was
// latency-bound at 106us: VGPR=64 -> compiler serialized staging loads).
#define BM 64
#define BK 64
#define LDK 72   // padded row stride in halfs (144 B: 16B-aligned, bank-spread)

__global__ __launch_bounds__(640, 2) void gemm_kernel(
    const float* __restrict__ hidden, const ushort_t* __restrict__ Wc,
    const float* __restrict__ b_ts, const float* __restrict__ b_tr,
    float* __restrict__ base_logits, float* __restrict__ pooled_ts)
{
  __shared__ ushort_t Alds[BM * LDK];      //  9216 B
  __shared__ ushort_t Blds[N_DIM * LDK];   // 46080 B
  const int tid = threadIdx.x;
  const int lane = tid & 63;
  const int w = tid >> 6;        // 0..9
  const int wc = w % 5;          // N-slice of 64
  const int wrr = w / 5;         // M-slice of 32
  const int row0 = blockIdx.x * BM;
  const int lr = lane & 15;
  const int lgp = lane >> 4;
  const bool hasA2 = (tid < 384);          // 1024 A-f4-chunks over 640 threads

  // precomputed staging addresses
  const int ar0 = tid >> 4, ac0 = (tid & 15) * 4;
  const int ar1 = (tid + 640) >> 4, ac1 = ((tid + 640) & 15) * 4;

  facc_t acc[2][4];
#pragma unroll
  for (int mi = 0; mi < 2; mi++)
#pragma unroll
    for (int ni = 0; ni < 4; ni++) acc[mi][ni] = (facc_t){0.f, 0.f, 0.f, 0.f};

  f4_t vaA0, vaA1, vbA0, vbA1;   // ping set: A0/A1 (f32x4), B in u32x4 below
  u32x4_t vb0_0, vb0_1, vb0_2, vb0_3;
  f4_t vaB0, vaB1;
  u32x4_t vb1_0, vb1_1, vb1_2, vb1_3;

#define LOAD_TILE(k0, vA0, vA1, b0, b1, b2, b3)                                  \
  {                                                                              \
    vA0 = *reinterpret_cast<const f4_t*>(hidden + (size_t)(row0 + ar0) * K_DIM + (k0) + ac0); \
    if (hasA2)                                                                   \
      vA1 = *reinterpret_cast<const f4_t*>(hidden + (size_t)(row0 + ar1) * K_DIM + (k0) + ac1); \
    b0 = *reinterpret_cast<const u32x4_t*>(Wc + (size_t)(tid >> 3) * K_DIM + (k0) + (tid & 7) * 8); \
    b1 = *reinterpret_cast<const u32x4_t*>(Wc + (size_t)((tid + 640) >> 3) * K_DIM + (k0) + ((tid + 640) & 7) * 8); \
    b2 = *reinterpret_cast<const u32x4_t*>(Wc + (size_t)((tid + 1280) >> 3) * K_DIM + (k0) + ((tid + 1280) & 7) * 8); \
    b3 = *reinterpret_cast<const u32x4_t*>(Wc + (size_t)((tid + 1920) >> 3) * K_DIM + (k0) + ((tid + 1920) & 7) * 8); \
  }

#define STORE_TILE(vA0, vA1, b0, b1, b2, b3)                                     \
  {                                                                              \
    u16x4_t h;                                                                   \
    h[0] = f2bf(vA0[0]); h[1] = f2bf(vA0[1]); h[2] = f2bf(vA0[2]); h[3] = f2bf(vA0[3]); \
    *reinterpret_cast<u16x4_t*>(&Alds[ar0 * LDK + ac0]) = h;                     \
    if (hasA2) {                                                                 \
      h[0] = f2bf(vA1[0]); h[1] = f2bf(vA1[1]); h[2] = f2bf(vA1[2]); h[3] = f2bf(vA1[3]); \
      *reinterpret_cast<u16x4_t*>(&Alds[ar1 * LDK + ac1]) = h;                   \
    }                                                                            \
    *reinterpret_cast<u32x4_t*>(&Blds[(tid >> 3) * LDK + (tid & 7) * 8]) = b0;   \
    *reinterpret_cast<u32x4_t*>(&Blds[((tid + 640) >> 3) * LDK + ((tid + 640) & 7) * 8]) = b1; \
    *reinterpret_cast<u32x4_t*>(&Blds[((tid + 1280) >> 3) * LDK + ((tid + 1280) & 7) * 8]) = b2; \
    *reinterpret_cast<u32x4_t*>(&Blds[((tid + 1920) >> 3) * LDK + ((tid + 1920) & 7) * 8]) = b3; \
  }

#define COMPUTE_TILE()                                                           \
  {                                                                              \
    _Pragma("unroll")                                                            \
    for (int kk = 0; kk < 2; ++kk) {                                             \
      bfrag_t af[2], bfv[4];                                                     \
      _Pragma("unroll")                                                          \
      for (int mi = 0; mi < 2; mi++)                                             \
        af[mi] = *reinterpret_cast<const bfrag_t*>(&Alds[(wrr * 32 + mi * 16 + lr) * LDK + kk * 32 + lgp * 8]); \
      _Pragma("unroll")                                                          \
      for (int ni = 0; ni < 4; ni++)                                             \
        bfv[ni] = *reinterpret_cast<const bfrag_t*>(&Blds[(wc * 64 + ni * 16 + lr) * LDK + kk * 32 + lgp * 8]); \
      _Pragma("unroll")                                                          \
      for (int mi = 0; mi < 2; mi++)                                             \
        _Pragma("unroll")                                                        \
        for (int ni = 0; ni < 4; ni++)                                           \
          acc[mi][ni] = __builtin_amdgcn_mfma_f32_16x16x32_bf16(af[mi], bfv[ni], acc[mi][ni], 0, 0, 0); \
    }                                                                            \
  }

  // prologue: tile 0 into ping regs
  LOAD_TILE(0, vaA0, vaA1, vb0_0, vb0_1, vb0_2, vb0_3);

#pragma unroll 1
  for (int t = 0; t < 32; t += 2) {
    __syncthreads();                       // all waves done reading prev tile
    STORE_TILE(vaA0, vaA1, vb0_0, vb0_1, vb0_2, vb0_3);
    LOAD_TILE((t + 1) * BK, vaB0, vaB1, vb1_0, vb1_1, vb1_2, vb1_3);  // t+1<=31
    __syncthreads();                       // staging visible
    COMPUTE_TILE();                        // tile t

    __syncthreads();
    STORE_TILE(vaB0, vaB1, vb1_0, vb1_1, vb1_2, vb1_3);
    if (t + 2 < 32) LOAD_TILE((t + 2) * BK, vaA0, vaA1, vb0_0, vb0_1, vb0_2, vb0_3);
    __syncthreads();
    COMPUTE_TILE();                        // tile t+1
  }

  const int b = row0 >> 12;  // batch (4096 rows per batch, 64 | 4096)
  if (wc < 4) {
    // token_state columns: tanh then pool (sum over this wave's 32 rows)
#pragma unroll
    for (int ni = 0; ni < 4; ni++) {
      const int col = wc * 64 + ni * 16 + lr;
      const float bias = b_ts[col];
      float psum = 0.f;
#pragma unroll
      for (int mi = 0; mi < 2; mi++)
#pragma unroll
        for (int j = 0; j < 4; j++)
          psum += tanhf(acc[mi][ni][j] + bias);
      psum += __shfl_xor(psum, 16, 64);
      psum += __shfl_xor(psum, 32, 64);
      if (lgp == 0) atomicAdd(&pooled_ts[b * D_DIM + col], psum);
    }
  } else {
    // base logit columns (wc == 4 -> cols 256..319)
#pragma unroll
    for (int ni = 0; ni < 4; ni++) {
      const int e = ni * 16 + lr;
      const float bias = b_tr[e];
#pragma unroll
      for (int mi = 0; mi < 2; mi++)
#pragma unroll
        for (int j = 0; j < 4; j++) {
          const int row = row0 + wrr * 32 + mi * 16 + lgp * 4 + j;
          base_logits[(size_t)row * E_DIM + e] = acc[mi][ni][j] + bias;
        }
    }
  }
}

// ---------------- per-round softmax / margins / pooling ---------------------
__global__ __launch_bounds__(256) void route_kernel(
    int round,
    const float* __restrict__ base_logits,
    const float* __restrict__ bias1, const float* __restrict__ bias2,
    const uchar* __restrict__ active, uchar* __restrict__ tag,
    float* __restrict__ margins, float* __restrict__ pw_out,
    float* __restrict__ out)
{
  __shared__ float sm[4][64];
  const int tid = threadIdx.x;
  const int lane = tid & 63;
  const int wid = tid >> 6;
  const int b = blockIdx.x >> 8;   // 16 tokens/block, 256 blocks/batch
  const int t0 = blockIdx.x * 16 + wid * 4;

  float bv1 = 0.f, bv2 = 0.f;
  if (round >= 1) bv1 = bias1[b * E_DIM + lane];
  if (round == 2) bv2 = bias2[b * E_DIM + lane];

  float lg[4];
#pragma unroll
  for (int i = 0; i < 4; ++i)
    lg[i] = base_logits[(size_t)(t0 + i) * E_DIM + lane];

  if (round == 1) {
    uchar a[4];
#pragma unroll
    for (int i = 0; i < 4; ++i) a[i] = active[t0 + i];
#pragma unroll
    for (int i = 0; i < 4; ++i) {
      if (lane == 0) tag[t0 + i] = a[i];
      if (a[i]) lg[i] += bv1;
    }
  } else if (round == 2) {
    uchar a[4], tg[4];
#pragma unroll
    for (int i = 0; i < 4; ++i) { a[i] = active[t0 + i]; tg[i] = tag[t0 + i]; }
#pragma unroll
    for (int i = 0; i < 4; ++i)
      lg[i] += a[i] ? bv2 : (tg[i] ? bv1 : 0.f);
  }

  float pacc = 0.f;
#pragma unroll
  for (int i = 0; i < 4; ++i) {
    const float lgt = lg[i];
    float m1 = lgt;
#pragma unroll
    for (int mm = 32; mm; mm >>= 1) m1 = fmaxf(m1, __shfl_xor(m1, mm, 64));
    float e = expf(lgt - m1);
    float s = e;
#pragma unroll
    for (int mm = 32; mm; mm >>= 1) s += __shfl_xor(s, mm, 64);
    if (round == 2) {
      out[(size_t)(t0 + i) * E_DIM + lane] = e / s;
    } else {
      pacc += e / s;
      unsigned long long bal = __ballot(lgt == m1);
      int first = __ffsll((unsigned long long)bal) - 1;
      float l2 = (lane == first) ? -__builtin_inff() : lgt;
#pragma unroll
      for (int mm = 32; mm; mm >>= 1) l2 = fmaxf(l2, __shfl_xor(l2, mm, 64));
      if (lane == 0) margins[t0 + i] = (1.f - expf(l2 - m1)) / s;  // top1-top2 of weights
    }
  }
  if (round != 2) {
    sm[wid][lane] = pacc;
    __syncthreads();
    if (wid == 0) {
      float v = sm[0][lane] + sm[1][lane] + sm[2][lane] + sm[3][lane];
      atomicAdd(&pw_out[b * E_DIM + lane], v);
    }
  }
}

// ---------------- mid: GRU (blocks 0..3) + k-smallest select (block 4) ------
__global__ __launch_bounds__(1024) void mid_kernel(
    const float* __restrict__ margins,
    const float* __restrict__ pw,
    const float* __restrict__ W_fb, const float* __restrict__ W_r, const float* __restrict__ b_r,
    const float* __restrict__ W_z, const float* __restrict__ b_z,
    const float* __restrict__ W_ci, const float* __restrict__ b_ci,
    const float* __restrict__ W_cs, const float* __restrict__ W_sr,
    const float* __restrict__ pooled_ts, float* __restrict__ ctrl,
    float* __restrict__ bias_out, uchar* __restrict__ active)
{
  const int tid = threadIdx.x;
  const int lane = tid & 63;
  const int wid = tid >> 6;      // 0..15
  if (blockIdx.x < 4) {
    __shared__ float si[256], rcs[256], zgs[256], ais[256], cns[256];
    const int b = blockIdx.x;
    const float pwv = pw[b * 64 + lane];
    // stage 0: si[d] = (pooled_ts + W_fb @ pw) / 4096
    for (int r = wid; r < 256; r += 16) {
      float v = W_fb[r * 64 + lane] * pwv;
      v = red64(v);
      if (lane == 0) si[r] = (pooled_ts[b * 256 + r] + v) * (1.f / 4096.f);
    }
    __syncthreads();
    // stage 1: three 256x256 matvecs (W_r, W_z, W_ci) @ si
    for (int t = wid; t < 768; t += 16) {
      const int m = t >> 8, r = t & 255;
      const float* Wm = (m == 0) ? W_r : (m == 1) ? W_z : W_ci;
      f4_t wv = *reinterpret_cast<const f4_t*>(&Wm[r * 256 + lane * 4]);
      f4_t xv = *reinterpret_cast<const f4_t*>(&si[lane * 4]);
      float v = wv[0] * xv[0] + wv[1] * xv[1] + wv[2] * xv[2] + wv[3] * xv[3];
      v = red64(v);
      if (lane == 0) {
        if (m == 0) {
          float rg = 1.f / (1.f + expf(-(v + b_r[r])));
          rcs[r] = rg * ctrl[b * 256 + r];
        } else if (m == 1) {
          zgs[r] = 1.f / (1.f + expf(-(v + b_z[r])));
        } else {
          ais[r] = v + b_ci[r];
        }
      }
    }
    __syncthreads();
    // stage 2: W_cs @ rc, then GRU combine
    for (int r = wid; r < 256; r += 16) {
      f4_t wv = *reinterpret_cast<const f4_t*>(&W_cs[r * 256 + lane * 4]);
      f4_t xv = *reinterpret_cast<const f4_t*>(&rcs[lane * 4]);
      float v = wv[0] * xv[0] + wv[1] * xv[1] + wv[2] * xv[2] + wv[3] * xv[3];
      v = red64(v);
      if (lane == 0) {
        float cold = ctrl[b * 256 + r];
        float zg = zgs[r];
        float cand = tanhf(ais[r] + v);
        float cnew = (1.f - zg) * cold + zg * cand;
        ctrl[b * 256 + r] = cnew;
        cns[r] = cnew;
      }
    }
    __syncthreads();
    // stage 3: route bias = W_sr @ ctrl  (64 rows)
    for (int r = wid; r < 64; r += 16) {
      f4_t wv = *reinterpret_cast<const f4_t*>(&W_sr[r * 256 + lane * 4]);
      f4_t xv = *reinterpret_cast<const f4_t*>(&cns[lane * 4]);
      float v = wv[0] * xv[0] + wv[1] * xv[1] + wv[2] * xv[2] + wv[3] * xv[3];
      v = red64(v);
      if (lane == 0) bias_out[b * 64 + r] = v;
    }
  } else {
    // exact k-smallest radix select (margins >= 0 -> uint order == float order)
    __shared__ uint hist[256];
    __shared__ uint aux2[4];     // [0]=pick [1]=kknew [2]=c_lt [3]=need
    __shared__ uint wsum[16];
    const u32x4_t* mv = reinterpret_cast<const u32x4_t*>(margins);
    uint pfx = 0, kk = KSEL;
    for (int shift = 24; shift >= 0; shift -= 8) {
      if (tid < 256) hist[tid] = 0;
      __syncthreads();
#pragma unroll
      for (int p = 0; p < 4; ++p) {
        u32x4_t v = mv[p * 1024 + tid];
#pragma unroll
        for (int e = 0; e < 4; ++e) {
          uint u = v[e];
          bool ok = (shift == 24) || ((u >> (shift + 8)) == (pfx >> (shift + 8)));
          uint bin = (u >> shift) & 255u;
          unsigned long long m = __ballot(ok);
#pragma unroll
          for (int bit = 0; bit < 8; ++bit) {
            unsigned long long bb = __ballot(ok && ((bin >> bit) & 1u));
            m &= ((bin >> bit) & 1u) ? bb : ~bb;
          }
          if (ok && (__ffsll(m) - 1) == lane) atomicAdd(&hist[bin], (uint)__popcll(m));
        }
      }
      __syncthreads();
      // parallel inclusive scan over hist[256] (4 waves) — replaces the
      // tid==0 serial 256-iteration LDS-latency chain
      uint hv = 0, hx = 0;
      if (tid < 256) {
        hv = hist[tid];
        hx = hv;
#pragma unroll
        for (int d = 1; d < 64; d <<= 1) {
          uint y = __shfl_up(hx, d, 64);
          if (lane >= d) hx += y;
        }
        if (lane == 63) wsum[wid] = hx;
      }
      __syncthreads();
      if (tid < 256) {
        uint base = 0;
        for (int w2 = 0; w2 < 4; ++w2) base += (w2 < wid) ? wsum[w2] : 0u;
        uint inc = hx + base;
        if (inc >= kk && (inc - hv) < kk) { aux2[0] = (uint)tid; aux2[1] = kk - (inc - hv); }
      }
      __syncthreads();
      pfx |= aux2[0] << shift;
      kk = aux2[1];
      __syncthreads();
    }
    const uint tval = pfx;
    if (tid == 0) aux2[2] = 0;
    __syncthreads();
    // count lt / stable rank of equals; each thread owns 16 contiguous elems
    uint myLt = 0, myEq = 0;
    u32x4_t loc[4];
#pragma unroll
    for (int q = 0; q < 4; ++q) {
      loc[q] = mv[tid * 4 + q];
#pragma unroll
      for (int e = 0; e < 4; ++e) {
        uint u = loc[q][e];
        myLt += (u < tval) ? 1u : 0u;
        myEq += (u == tval) ? 1u : 0u;
      }
    }
    uint lt = myLt;
#pragma unroll
    for (int m = 32; m; m >>= 1) lt += __shfl_xor(lt, m, 64);
    if (lane == 0) atomicAdd(&aux2[2], lt);
    uint x = myEq;
#pragma unroll
    for (int d = 1; d < 64; d <<= 1) {
      uint y = __shfl_up(x, d, 64);
      if (lane >= d) x += y;
    }
    if (lane == 63) wsum[wid] = x;
    __syncthreads();
    if (tid == 0) {
      uint run = 0;
      for (int w2 = 0; w2 < 16; ++w2) { uint c = wsum[w2]; wsum[w2] = run; run += c; }
      aux2[3] = (uint)KSEL - aux2[2];
    }
    __syncthreads();
    uint pos = wsum[wid] + (x - myEq);
    const uint need = aux2[3];
#pragma unroll
    for (int q = 0; q < 4; ++q) {
#pragma unroll
      for (int e = 0; e < 4; ++e) {
        uint u = loc[q][e];
        uchar a = 0;
        if (u < tval) a = 1;
        else if (u == tval) { a = (pos < need) ? 1 : 0; pos++; }
        active[tid * 16 + q * 4 + e] = a;
      }
    }
  }
}

// ---------------- launch ----------------------------------------------------
extern "C" void kernel_launch(void* const* d_in, const int* in_sizes, int n_in,
                              void* d_out, int out_size, void* d_ws, size_t ws_size,
                              hipStream_t stream) {
  const float* hidden = (const float*)d_in[0];
  const float* W_ts = (const float*)d_in[1];
  const float* b_ts = (const float*)d_in[2];
  const float* W_tr = (const float*)d_in[3];
  const float* b_tr = (const float*)d_in[4];
  const float* W_sr = (const float*)d_in[5];
  const float* W_fb = (const float*)d_in[6];
  const float* W_r  = (const float*)d_in[7];
  const float* b_r  = (const float*)d_in[8];
  const float* W_z  = (const float*)d_in[9];
  const float* b_z  = (const float*)d_in[10];
  const float* W_ci = (const float*)d_in[11];
  const float* b_ci = (const float*)d_in[12];
  const float* W_cs = (const float*)d_in[13];
  float* out = (float*)d_out;

  char* ws = (char*)d_ws;
  float* base_logits = (float*)(ws);                                   // 4 MB
  ushort_t* Wc = (ushort_t*)(ws + (4u << 20));                         // 1.25 MB
  float* margins = (float*)(ws + (4u << 20) + 1310720u);               // 64 KB
  uchar* active = (uchar*)(ws + (4u << 20) + 1310720u + 65536u);       // 16 KB
  uchar* tag    = (uchar*)(ws + (4u << 20) + 1310720u + 65536u + 16384u); // 16 KB
  float* pooled_ts = (float*)(ws + (4u << 20) + 1310720u + 65536u + 32768u);
  float* pw0   = pooled_ts + 1024;
  float* pw1   = pw0 + 256;
  float* ctrl  = pw1 + 256;     // end of contiguous zero_region (2560 floats)
  float* bias1 = ctrl + 1024;
  float* bias2 = bias1 + 256;

  prep_kernel<<<640, 256, 0, stream>>>(W_ts, W_tr, Wc, pooled_ts);
  gemm_kernel<<<256, 640, 0, stream>>>(hidden, Wc, b_ts, b_tr, base_logits, pooled_ts);
  route_kernel<<<1024, 256, 0, stream>>>(0, base_logits, nullptr, nullptr, nullptr, nullptr,
                                         margins, pw0, nullptr);
  mid_kernel<<<5, 1024, 0, stream>>>(margins, pw0, W_fb, W_r, b_r, W_z, b_z, W_ci, b_ci,
                                     W_cs, W_sr, pooled_ts, ctrl, bias1, active);
  route_kernel<<<1024, 256, 0, stream>>>(1, base_logits, bias1, nullptr, active, tag,
                                         margins, pw1, nullptr);
  mid_kernel<<<5, 1024, 0, stream>>>(margins, pw1, W_fb, W_r, b_r, W_z, b_z, W_ci, b_ci,
                                     W_cs, W_sr, pooled_ts, ctrl, bias2, active);
  route_kernel<<<1024, 256, 0, stream>>>(2, base_logits, bias1, bias2, active, tag,
                                         nullptr, nullptr, out);
}

// Round 7
// 350.271 us; speedup vs baseline: 1.4879x; 1.1438x over previous
//
#include <hip/hip_runtime.h>
#include <hip/hip_bf16.h>
#include <math.h>

typedef unsigned int uint;
typedef unsigned short ushort_t;
typedef unsigned char uchar;

typedef __attribute__((ext_vector_type(4))) float f4_t;
typedef __attribute__((ext_vector_type(4))) ushort_t u16x4_t;
typedef __attribute__((ext_vector_type(4))) uint u32x4_t;
typedef __attribute__((ext_vector_type(8))) short bfrag_t;
typedef __attribute__((ext_vector_type(4))) float facc_t;

#define K_DIM 2048
#define D_DIM 256
#define E_DIM 64
#define N_DIM 320
#define S_DIM 4096
#define NTOK 16384
#define KSEL 4096

__device__ __forceinline__ ushort_t f2bf(float f) {
  uint u = __float_as_uint(f);
  uint r = u + 0x7FFFu + ((u >> 16) & 1u);  // RNE
  return (ushort_t)(r >> 16);
}

// ---------------- prep: convert weights to bf16, zero accumulators ----------
__global__ __launch_bounds__(256) void prep_kernel(
    const float* __restrict__ W_ts, const float* __restrict__ W_tr,
    ushort_t* __restrict__ Wc, float* __restrict__ zero_region)
{
  int idx = blockIdx.x * 256 + threadIdx.x;       // over N_DIM*K_DIM/4 float4s
  if (idx < (N_DIM * K_DIM / 4)) {
    int n = idx >> 9;                              // / (2048/4)
    int k4 = (idx & 511) * 4;
    const float* src = (n < D_DIM) ? (W_ts + (size_t)n * K_DIM + k4)
                                   : (W_tr + (size_t)(n - D_DIM) * K_DIM + k4);
    f4_t v = *reinterpret_cast<const f4_t*>(src);
    u16x4_t h;
    h[0] = f2bf(v[0]); h[1] = f2bf(v[1]); h[2] = f2bf(v[2]); h[3] = f2bf(v[3]);
    *reinterpret_cast<u16x4_t*>(&Wc[(size_t)n * K_DIM + k4]) = h;
  }
  if (blockIdx.x == 0) {
    for (int i = threadIdx.x; i < 2560; i += 256) zero_region[i] = 0.f;
  }
}

// ---------------- fused GEMM: base_logits + pooled tanh(token_state) --------
#define BM 64
#define BK 64
#define LDK 72   // padded row stride in halfs (144 B: 16B-aligned, bank-spread)

__global__ __launch_bounds__(640, 2) void gemm_kernel(
    const float* __restrict__ hidden, const ushort_t* __restrict__ Wc,
    const float* __restrict__ b_ts, const float* __restrict__ b_tr,
    float* __restrict__ base_logits, float* __restrict__ pooled_ts)
{
  __shared__ ushort_t Alds[BM * LDK];      //  9216 B
  __shared__ ushort_t Blds[N_DIM * LDK];   // 46080 B
  const int tid = threadIdx.x;
  const int lane = tid & 63;
  const int w = tid >> 6;        // 0..9
  const int wc = w % 5;          // N-slice of 64
  const int wrr = w / 5;         // M-slice of 32
  const int row0 = blockIdx.x * BM;
  const int lr = lane & 15;
  const int lgp = lane >> 4;
  const bool hasA2 = (tid < 384);          // 1024 A-f4-chunks over 640 threads

  const int ar0 = tid >> 4, ac0 = (tid & 15) * 4;
  const int ar1 = (tid + 640) >> 4, ac1 = ((tid + 640) & 15) * 4;

  facc_t acc[2][4];
#pragma unroll
  for (int mi = 0; mi < 2; mi++)
#pragma unroll
    for (int ni = 0; ni < 4; ni++) acc[mi][ni] = (facc_t){0.f, 0.f, 0.f, 0.f};

  f4_t vaA0, vaA1;
  u32x4_t vb0_0, vb0_1, vb0_2, vb0_3;
  f4_t vaB0, vaB1;
  u32x4_t vb1_0, vb1_1, vb1_2, vb1_3;

#define LOAD_TILE(k0, vA0, vA1, b0, b1, b2, b3)                                  \
  {                                                                              \
    vA0 = *reinterpret_cast<const f4_t*>(hidden + (size_t)(row0 + ar0) * K_DIM + (k0) + ac0); \
    if (hasA2)                                                                   \
      vA1 = *reinterpret_cast<const f4_t*>(hidden + (size_t)(row0 + ar1) * K_DIM + (k0) + ac1); \
    b0 = *reinterpret_cast<const u32x4_t*>(Wc + (size_t)(tid >> 3) * K_DIM + (k0) + (tid & 7) * 8); \
    b1 = *reinterpret_cast<const u32x4_t*>(Wc + (size_t)((tid + 640) >> 3) * K_DIM + (k0) + ((tid + 640) & 7) * 8); \
    b2 = *reinterpret_cast<const u32x4_t*>(Wc + (size_t)((tid + 1280) >> 3) * K_DIM + (k0) + ((tid + 1280) & 7) * 8); \
    b3 = *reinterpret_cast<const u32x4_t*>(Wc + (size_t)((tid + 1920) >> 3) * K_DIM + (k0) + ((tid + 1920) & 7) * 8); \
  }

#define STORE_TILE(vA0, vA1, b0, b1, b2, b3)                                     \
  {                                                                              \
    u16x4_t h;                                                                   \
    h[0] = f2bf(vA0[0]); h[1] = f2bf(vA0[1]); h[2] = f2bf(vA0[2]); h[3] = f2bf(vA0[3]); \
    *reinterpret_cast<u16x4_t*>(&Alds[ar0 * LDK + ac0]) = h;                     \
    if (hasA2) {                                                                 \
      h[0] = f2bf(vA1[0]); h[1] = f2bf(vA1[1]); h[2] = f2bf(vA1[2]); h[3] = f2bf(vA1[3]); \
      *reinterpret_cast<u16x4_t*>(&Alds[ar1 * LDK + ac1]) = h;                   \
    }                                                                            \
    *reinterpret_cast<u32x4_t*>(&Blds[(tid >> 3) * LDK + (tid & 7) * 8]) = b0;   \
    *reinterpret_cast<u32x4_t*>(&Blds[((tid + 640) >> 3) * LDK + ((tid + 640) & 7) * 8]) = b1; \
    *reinterpret_cast<u32x4_t*>(&Blds[((tid + 1280) >> 3) * LDK + ((tid + 1280) & 7) * 8]) = b2; \
    *reinterpret_cast<u32x4_t*>(&Blds[((tid + 1920) >> 3) * LDK + ((tid + 1920) & 7) * 8]) = b3; \
  }

#define COMPUTE_TILE()                                                           \
  {                                                                              \
    _Pragma("unroll")                                                            \
    for (int kk = 0; kk < 2; ++kk) {                                             \
      bfrag_t af[2], bfv[4];                                                     \
      _Pragma("unroll")                                                          \
      for (int mi = 0; mi < 2; mi++)                                             \
        af[mi] = *reinterpret_cast<const bfrag_t*>(&Alds[(wrr * 32 + mi * 16 + lr) * LDK + kk * 32 + lgp * 8]); \
      _Pragma("unroll")                                                          \
      for (int ni = 0; ni < 4; ni++)                                             \
        bfv[ni] = *reinterpret_cast<const bfrag_t*>(&Blds[(wc * 64 + ni * 16 + lr) * LDK + kk * 32 + lgp * 8]); \
      _Pragma("unroll")                                                          \
      for (int mi = 0; mi < 2; mi++)                                             \
        _Pragma("unroll")                                                        \
        for (int ni = 0; ni < 4; ni++)                                           \
          acc[mi][ni] = __builtin_amdgcn_mfma_f32_16x16x32_bf16(af[mi], bfv[ni], acc[mi][ni], 0, 0, 0); \
    }                                                                            \
  }

  LOAD_TILE(0, vaA0, vaA1, vb0_0, vb0_1, vb0_2, vb0_3);

#pragma unroll 1
  for (int t = 0; t < 32; t += 2) {
    __syncthreads();
    STORE_TILE(vaA0, vaA1, vb0_0, vb0_1, vb0_2, vb0_3);
    LOAD_TILE((t + 1) * BK, vaB0, vaB1, vb1_0, vb1_1, vb1_2, vb1_3);
    __syncthreads();
    COMPUTE_TILE();

    __syncthreads();
    STORE_TILE(vaB0, vaB1, vb1_0, vb1_1, vb1_2, vb1_3);
    if (t + 2 < 32) LOAD_TILE((t + 2) * BK, vaA0, vaA1, vb0_0, vb0_1, vb0_2, vb0_3);
    __syncthreads();
    COMPUTE_TILE();
  }

  const int b = row0 >> 12;  // batch (4096 rows per batch, 64 | 4096)
  if (wc < 4) {
#pragma unroll
    for (int ni = 0; ni < 4; ni++) {
      const int col = wc * 64 + ni * 16 + lr;
      const float bias = b_ts[col];
      float psum = 0.f;
#pragma unroll
      for (int mi = 0; mi < 2; mi++)
#pragma unroll
        for (int j = 0; j < 4; j++)
          psum += tanhf(acc[mi][ni][j] + bias);
      psum += __shfl_xor(psum, 16, 64);
      psum += __shfl_xor(psum, 32, 64);
      if (lgp == 0) atomicAdd(&pooled_ts[b * D_DIM + col], psum);
    }
  } else {
#pragma unroll
    for (int ni = 0; ni < 4; ni++) {
      const int e = ni * 16 + lr;
      const float bias = b_tr[e];
#pragma unroll
      for (int mi = 0; mi < 2; mi++)
#pragma unroll
        for (int j = 0; j < 4; j++) {
          const int row = row0 + wrr * 32 + mi * 16 + lgp * 4 + j;
          base_logits[(size_t)row * E_DIM + e] = acc[mi][ni][j] + bias;
        }
    }
  }
}

// ---------------- per-round softmax / margins / pooling ---------------------
__global__ __launch_bounds__(256) void route_kernel(
    int round,
    const float* __restrict__ base_logits,
    const float* __restrict__ bias1, const float* __restrict__ bias2,
    const uchar* __restrict__ active, uchar* __restrict__ tag,
    float* __restrict__ margins, float* __restrict__ pw_out,
    float* __restrict__ out)
{
  __shared__ float sm[4][64];
  const int tid = threadIdx.x;
  const int lane = tid & 63;
  const int wid = tid >> 6;
  const int b = blockIdx.x >> 8;   // 16 tokens/block, 256 blocks/batch
  const int t0 = blockIdx.x * 16 + wid * 4;

  float bv1 = 0.f, bv2 = 0.f;
  if (round >= 1) bv1 = bias1[b * E_DIM + lane];
  if (round == 2) bv2 = bias2[b * E_DIM + lane];

  float lg[4];
#pragma unroll
  for (int i = 0; i < 4; ++i)
    lg[i] = base_logits[(size_t)(t0 + i) * E_DIM + lane];

  if (round == 1) {
    uchar a[4];
#pragma unroll
    for (int i = 0; i < 4; ++i) a[i] = active[t0 + i];
#pragma unroll
    for (int i = 0; i < 4; ++i) {
      if (lane == 0) tag[t0 + i] = a[i];
      if (a[i]) lg[i] += bv1;
    }
  } else if (round == 2) {
    uchar a[4], tg[4];
#pragma unroll
    for (int i = 0; i < 4; ++i) { a[i] = active[t0 + i]; tg[i] = tag[t0 + i]; }
#pragma unroll
    for (int i = 0; i < 4; ++i)
      lg[i] += a[i] ? bv2 : (tg[i] ? bv1 : 0.f);
  }

  float pacc = 0.f;
#pragma unroll
  for (int i = 0; i < 4; ++i) {
    const float lgt = lg[i];
    float m1 = lgt;
#pragma unroll
    for (int mm = 32; mm; mm >>= 1) m1 = fmaxf(m1, __shfl_xor(m1, mm, 64));
    float e = expf(lgt - m1);
    float s = e;
#pragma unroll
    for (int mm = 32; mm; mm >>= 1) s += __shfl_xor(s, mm, 64);
    if (round == 2) {
      out[(size_t)(t0 + i) * E_DIM + lane] = e / s;
    } else {
      pacc += e / s;
      unsigned long long bal = __ballot(lgt == m1);
      int first = __ffsll((unsigned long long)bal) - 1;
      float l2 = (lane == first) ? -__builtin_inff() : lgt;
#pragma unroll
      for (int mm = 32; mm; mm >>= 1) l2 = fmaxf(l2, __shfl_xor(l2, mm, 64));
      if (lane == 0) margins[t0 + i] = (1.f - expf(l2 - m1)) / s;  // top1-top2 of weights
    }
  }
  if (round != 2) {
    sm[wid][lane] = pacc;
    __syncthreads();
    if (wid == 0) {
      float v = sm[0][lane] + sm[1][lane] + sm[2][lane] + sm[3][lane];
      atomicAdd(&pw_out[b * E_DIM + lane], v);
    }
  }
}

// ---------------- mid: GRU (blocks 0..3, one per batch) + select (block 4) --
// R6 post-mortem: 95us at VGPR=20 / VALUBusy 0.4% — zero memory-level
// parallelism; every row-dot was a serial ~1000cy round trip. Fix: thread-
// per-output-row with #pragma unroll 16 f4 loads (16 loads in flight), si/
// rcs/cns staged in LDS; select loads its 16 elems to registers ONCE and
// runs all radix passes from registers.
__global__ __launch_bounds__(1024) void mid_kernel(
    const float* __restrict__ margins,
    const float* __restrict__ pw,
    const float* __restrict__ W_fb, const float* __restrict__ W_r, const float* __restrict__ b_r,
    const float* __restrict__ W_z, const float* __restrict__ b_z,
    const float* __restrict__ W_ci, const float* __restrict__ b_ci,
    const float* __restrict__ W_cs, const float* __restrict__ W_sr,
    const float* __restrict__ pooled_ts, float* __restrict__ ctrl,
    float* __restrict__ bias_out, uchar* __restrict__ active)
{
  const int tid = threadIdx.x;
  const int lane = tid & 63;
  const int wid = tid >> 6;      // 0..15
  if (blockIdx.x < 4) {
    __shared__ float si[256], rcs[256], zgs[256], ais[256], cns[256], pwl[64];
    const int b = blockIdx.x;
    if (tid < 64) pwl[tid] = pw[b * 64 + tid];
    __syncthreads();
    // stage 0: threads 0-255: si[r] = (pooled_ts + W_fb@pw)/4096
    if (tid < 256) {
      const float* wr = W_fb + tid * 64;
      float pv = pooled_ts[b * 256 + tid];
      float s = 0.f;
#pragma unroll
      for (int j = 0; j < 16; ++j) {
        f4_t wv = *reinterpret_cast<const f4_t*>(wr + j * 4);
        s += wv[0] * pwl[j * 4] + wv[1] * pwl[j * 4 + 1]
           + wv[2] * pwl[j * 4 + 2] + wv[3] * pwl[j * 4 + 3];
      }
      si[tid] = (pv + s) * (1.f / 4096.f);
    }
    __syncthreads();
    // stage 1: threads 0-767: row r of mat m in {W_r, W_z, W_ci} @ si
    if (tid < 768) {
      const int m = tid >> 8, r = tid & 255;
      const float* wr = ((m == 0) ? W_r : (m == 1) ? W_z : W_ci) + r * 256;
      float cold = (m == 0) ? ctrl[b * 256 + r] : 0.f;   // issue early
      float s = 0.f;
#pragma unroll 16
      for (int j = 0; j < 64; ++j) {
        f4_t wv = *reinterpret_cast<const f4_t*>(wr + j * 4);
        f4_t xv = *reinterpret_cast<const f4_t*>(&si[j * 4]);
        s += wv[0] * xv[0] + wv[1] * xv[1] + wv[2] * xv[2] + wv[3] * xv[3];
      }
      if (m == 0)      rcs[r] = cold / (1.f + expf(-(s + b_r[r])));
      else if (m == 1) zgs[r] = 1.f / (1.f + expf(-(s + b_z[r])));
      else             ais[r] = s + b_ci[r];
    }
    __syncthreads();
    // stage 2: threads 0-255: W_cs @ rcs, GRU combine
    if (tid < 256) {
      const float* wr = W_cs + tid * 256;
      float cold = ctrl[b * 256 + tid];
      float s = 0.f;
#pragma unroll 16
      for (int j = 0; j < 64; ++j) {
        f4_t wv = *reinterpret_cast<const f4_t*>(wr + j * 4);
        f4_t xv = *reinterpret_cast<const f4_t*>(&rcs[j * 4]);
        s += wv[0] * xv[0] + wv[1] * xv[1] + wv[2] * xv[2] + wv[3] * xv[3];
      }
      float zg = zgs[tid];
      float cnew = (1.f - zg) * cold + zg * tanhf(ais[tid] + s);
      ctrl[b * 256 + tid] = cnew;
      cns[tid] = cnew;
    }
    __syncthreads();
    // stage 3: threads 0-255, 4 lanes per row: bias = W_sr @ cns (64 rows)
    if (tid < 256) {
      const int r = tid >> 2, q = tid & 3;
      const float* wr = W_sr + r * 256 + q * 64;
      float s = 0.f;
#pragma unroll
      for (int j = 0; j < 16; ++j) {
        f4_t wv = *reinterpret_cast<const f4_t*>(wr + j * 4);
        f4_t xv = *reinterpret_cast<const f4_t*>(&cns[q * 64 + j * 4]);
        s += wv[0] * xv[0] + wv[1] * xv[1] + wv[2] * xv[2] + wv[3] * xv[3];
      }
      s += __shfl_xor(s, 1, 64);
      s += __shfl_xor(s, 2, 64);
      if (q == 0) bias_out[b * 64 + r] = s;
    }
  } else {
    // exact k-smallest radix select; all 4 passes run from registers
    __shared__ uint hist[256];
    __shared__ uint aux2[4];     // [0]=pick [1]=kknew [2]=c_lt [3]=need
    __shared__ uint wsum[16];
    const u32x4_t* mv = reinterpret_cast<const u32x4_t*>(margins);
    u32x4_t loc[4];
#pragma unroll
    for (int q = 0; q < 4; ++q) loc[q] = mv[tid * 4 + q];  // 16 contiguous elems, once
    uint pfx = 0, kk = KSEL;
    for (int shift = 24; shift >= 0; shift -= 8) {
      if (tid < 256) hist[tid] = 0;
      __syncthreads();
#pragma unroll
      for (int q = 0; q < 4; ++q) {
#pragma unroll
        for (int e = 0; e < 4; ++e) {
          uint u = loc[q][e];
          bool ok = (shift == 24) || ((u >> (shift + 8)) == (pfx >> (shift + 8)));
          uint bin = (u >> shift) & 255u;
          unsigned long long m = __ballot(ok);
#pragma unroll
          for (int bit = 0; bit < 8; ++bit) {
            unsigned long long bb = __ballot(ok && ((bin >> bit) & 1u));
            m &= ((bin >> bit) & 1u) ? bb : ~bb;
          }
          if (ok && (__ffsll(m) - 1) == lane) atomicAdd(&hist[bin], (uint)__popcll(m));
        }
      }
      __syncthreads();
      // parallel inclusive scan over hist[256] (4 waves)
      uint hv = 0, hx = 0;
      if (tid < 256) {
        hv = hist[tid];
        hx = hv;
#pragma unroll
        for (int d = 1; d < 64; d <<= 1) {
          uint y = __shfl_up(hx, d, 64);
          if (lane >= d) hx += y;
        }
        if (lane == 63) wsum[wid] = hx;
      }
      __syncthreads();
      if (tid < 256) {
        uint base = 0;
        for (int w2 = 0; w2 < 4; ++w2) base += (w2 < wid) ? wsum[w2] : 0u;
        uint inc = hx + base;
        if (inc >= kk && (inc - hv) < kk) { aux2[0] = (uint)tid; aux2[1] = kk - (inc - hv); }
      }
      __syncthreads();
      pfx |= aux2[0] << shift;
      kk = aux2[1];
      __syncthreads();
    }
    const uint tval = pfx;
    if (tid == 0) aux2[2] = 0;
    __syncthreads();
    // count lt / stable rank of equals (16 contiguous elems per thread)
    uint myLt = 0, myEq = 0;
#pragma unroll
    for (int q = 0; q < 4; ++q) {
#pragma unroll
      for (int e = 0; e < 4; ++e) {
        uint u = loc[q][e];
        myLt += (u < tval) ? 1u : 0u;
        myEq += (u == tval) ? 1u : 0u;
      }
    }
    uint lt = myLt;
#pragma unroll
    for (int m = 32; m; m >>= 1) lt += __shfl_xor(lt, m, 64);
    if (lane == 0) atomicAdd(&aux2[2], lt);
    uint x = myEq;
#pragma unroll
    for (int d = 1; d < 64; d <<= 1) {
      uint y = __shfl_up(x, d, 64);
      if (lane >= d) x += y;
    }
    if (lane == 63) wsum[wid] = x;
    __syncthreads();
    if (tid == 0) {
      uint run = 0;
      for (int w2 = 0; w2 < 16; ++w2) { uint c = wsum[w2]; wsum[w2] = run; run += c; }
      aux2[3] = (uint)KSEL - aux2[2];
    }
    __syncthreads();
    uint pos = wsum[wid] + (x - myEq);
    const uint need = aux2[3];
#pragma unroll
    for (int q = 0; q < 4; ++q) {
#pragma unroll
      for (int e = 0; e < 4; ++e) {
        uint u = loc[q][e];
        uchar a = 0;
        if (u < tval) a = 1;
        else if (u == tval) { a = (pos < need) ? 1 : 0; pos++; }
        active[tid * 16 + q * 4 + e] = a;
      }
    }
  }
}

// ---------------- launch ----------------------------------------------------
extern "C" void kernel_launch(void* const* d_in, const int* in_sizes, int n_in,
                              void* d_out, int out_size, void* d_ws, size_t ws_size,
                              hipStream_t stream) {
  const float* hidden = (const float*)d_in[0];
  const float* W_ts = (const float*)d_in[1];
  const float* b_ts = (const float*)d_in[2];
  const float* W_tr = (const float*)d_in[3];
  const float* b_tr = (const float*)d_in[4];
  const float* W_sr = (const float*)d_in[5];
  const float* W_fb = (const float*)d_in[6];
  const float* W_r  = (const float*)d_in[7];
  const float* b_r  = (const float*)d_in[8];
  const float* W_z  = (const float*)d_in[9];
  const float* b_z  = (const float*)d_in[10];
  const float* W_ci = (const float*)d_in[11];
  const float* b_ci = (const float*)d_in[12];
  const float* W_cs = (const float*)d_in[13];
  float* out = (float*)d_out;

  char* ws = (char*)d_ws;
  float* base_logits = (float*)(ws);                                   // 4 MB
  ushort_t* Wc = (ushort_t*)(ws + (4u << 20));                         // 1.25 MB
  float* margins = (float*)(ws + (4u << 20) + 1310720u);               // 64 KB
  uchar* active = (uchar*)(ws + (4u << 20) + 1310720u + 65536u);       // 16 KB
  uchar* tag    = (uchar*)(ws + (4u << 20) + 1310720u + 65536u + 16384u); // 16 KB
  float* pooled_ts = (float*)(ws + (4u << 20) + 1310720u + 65536u + 32768u);
  float* pw0   = pooled_ts + 1024;
  float* pw1   = pw0 + 256;
  float* ctrl  = pw1 + 256;     // end of contiguous zero_region (2560 floats)
  float* bias1 = ctrl + 1024;
  float* bias2 = bias1 + 256;

  prep_kernel<<<640, 256, 0, stream>>>(W_ts, W_tr, Wc, pooled_ts);
  gemm_kernel<<<256, 640, 0, stream>>>(hidden, Wc, b_ts, b_tr, base_logits, pooled_ts);
  route_kernel<<<1024, 256, 0, stream>>>(0, base_logits, nullptr, nullptr, nullptr, nullptr,
                                         margins, pw0, nullptr);
  mid_kernel<<<5, 1024, 0, stream>>>(margins, pw0, W_fb, W_r, b_r, W_z, b_z, W_ci, b_ci,
                                     W_cs, W_sr, pooled_ts, ctrl, bias1, active);
  route_kernel<<<1024, 256, 0, stream>>>(1, base_logits, bias1, nullptr, active, tag,
                                         margins, pw1, nullptr);
  mid_kernel<<<5, 1024, 0, stream>>>(margins, pw1, W_fb, W_r, b_r, W_z, b_z, W_ci, b_ci,
                                     W_cs, W_sr, pooled_ts, ctrl, bias2, active);
  route_kernel<<<1024, 256, 0, stream>>>(2, base_logits, bias1, bias2, active, tag,
                                         nullptr, nullptr, out);
}